// Round 1
// 1188.102 us; speedup vs baseline: 1.0574x; 1.0574x over previous
//
#include <hip/hip_runtime.h>
#include <math.h>

// ---------------------------------------------------------------------------
// Model dims (fixed by the reference)
// ---------------------------------------------------------------------------
#define BATCH   1024
#define NPG     32
#define NNODES  (BATCH * NPG)      // 32768 per drug
#define EPG     128
#define INFEAT  78
#define CCH     128
#define NHEAD   8
#define GENE    18000
#define GENEP   18048              // padded to %128 (8-phase kernel needs K%128)
#define PROT    6688
#define PROTP   6784               // padded to %128
#define FPD     2048

#define ACT_NONE 0
#define ACT_RELU 1
#define ACT_ELU  2

typedef unsigned short ushort_t;
typedef __bf16 bf16x8_t __attribute__((ext_vector_type(8)));
typedef float  f32x4_t  __attribute__((ext_vector_type(4)));

__device__ __forceinline__ float b2f(ushort_t u) {
    return __uint_as_float(((unsigned)u) << 16);
}
__device__ __forceinline__ ushort_t f2b(float f) {
    unsigned x = __float_as_uint(f);
    return (ushort_t)((x + 0x7fffu + ((x >> 16) & 1u)) >> 16);   // RNE
}

// ---------------------------------------------------------------------------
// bf16 MFMA GEMM (m97 structure): C[M,N] = act(A[M,K] @ BT[N,K]^T + bias)
// A, BT bf16 (K%32==0); C bf16; bias fp32. M%128==0, N%128==0.
// 128x128 tile, BK=32, 256 threads (2x2 waves of 64x64), global_load_lds.
// ---------------------------------------------------------------------------
#define GBM 128
#define GBN 128
#define GBK 32

__device__ __forceinline__ void gemm_core(
    const ushort_t* __restrict__ A, const ushort_t* __restrict__ BT,
    int K, int kb, int ke, int row0, int col0,
    ushort_t* Asl, ushort_t* Bsl, f32x4_t acc[4][4])
{
    const int tid  = threadIdx.x;
    const int wave = tid >> 6;
    const int lane = tid & 63;
    const int wr   = wave >> 1;
    const int wc   = wave & 1;
    const int srow = lane >> 2;        // 0..15
    const int skel = (lane & 3) * 8;   // bf16 elem offset

    for (int k0 = kb; k0 < ke; k0 += GBK) {
        __syncthreads();               // protect LDS from previous iteration
        #pragma unroll
        for (int t = 0; t < 2; ++t) {
            const int rg = wave * 32 + t * 16;                   // wave-uniform
            const ushort_t* ga = A + (size_t)(row0 + rg + srow) * K + k0 + skel;
            __builtin_amdgcn_global_load_lds(
                (const __attribute__((address_space(1))) void*)ga,
                (__attribute__((address_space(3))) void*)&Asl[rg * GBK], 16, 0, 0);
            const ushort_t* gb = BT + (size_t)(col0 + rg + srow) * K + k0 + skel;
            __builtin_amdgcn_global_load_lds(
                (const __attribute__((address_space(1))) void*)gb,
                (__attribute__((address_space(3))) void*)&Bsl[rg * GBK], 16, 0, 0);
        }
        __syncthreads();

        const int fr = lane & 15;
        const int fq = lane >> 4;
        bf16x8_t av[4], bv[4];
        #pragma unroll
        for (int i = 0; i < 4; ++i)
            av[i] = *(const bf16x8_t*)&Asl[(wr * 64 + i * 16 + fr) * GBK + fq * 8];
        #pragma unroll
        for (int j = 0; j < 4; ++j)
            bv[j] = *(const bf16x8_t*)&Bsl[(wc * 64 + j * 16 + fr) * GBK + fq * 8];
        #pragma unroll
        for (int i = 0; i < 4; ++i)
            #pragma unroll
            for (int j = 0; j < 4; ++j)
                acc[i][j] = __builtin_amdgcn_mfma_f32_16x16x32_bf16(
                    av[i], bv[j], acc[i][j], 0, 0, 0);
    }
}

__global__ __launch_bounds__(256) void gemm_bf16_kernel(
    const ushort_t* __restrict__ A, const ushort_t* __restrict__ BT,
    const float* __restrict__ bias, ushort_t* __restrict__ C,
    int M, int N, int K, int act)
{
    __shared__ ushort_t Asl[GBM * GBK];
    __shared__ ushort_t Bsl[GBN * GBK];
    const int lane = threadIdx.x & 63;
    const int wave = threadIdx.x >> 6;
    const int wr = wave >> 1, wc = wave & 1;
    const int row0 = blockIdx.y * GBM;
    const int col0 = blockIdx.x * GBN;

    f32x4_t acc[4][4] = {};
    gemm_core(A, BT, K, 0, K, row0, col0, Asl, Bsl, acc);

    const int fr = lane & 15;
    const int fq = lane >> 4;
    #pragma unroll
    for (int i = 0; i < 4; ++i) {
        #pragma unroll
        for (int j = 0; j < 4; ++j) {
            const int gn = col0 + wc * 64 + j * 16 + fr;
            const float bb = bias ? bias[gn] : 0.0f;
            #pragma unroll
            for (int r = 0; r < 4; ++r) {
                const int gm = row0 + wr * 64 + i * 16 + fq * 4 + r;
                float v = acc[i][j][r] + bb;
                if (act == ACT_RELU)     v = fmaxf(v, 0.0f);
                else if (act == ACT_ELU) v = (v > 0.0f) ? v : (expf(v) - 1.0f);
                C[(size_t)gm * N + gn] = f2b(v);
            }
        }
    }
}

// split-K variant: grid.z = chunk index, fp32 partials out (no bias/act)
__global__ __launch_bounds__(256) void gemm_bf16_part_kernel(
    const ushort_t* __restrict__ A, const ushort_t* __restrict__ BT,
    float* __restrict__ part, int M, int N, int K, int KC)
{
    __shared__ ushort_t Asl[GBM * GBK];
    __shared__ ushort_t Bsl[GBN * GBK];
    const int lane = threadIdx.x & 63;
    const int wave = threadIdx.x >> 6;
    const int wr = wave >> 1, wc = wave & 1;
    const int row0 = blockIdx.y * GBM;
    const int col0 = blockIdx.x * GBN;
    const int z    = blockIdx.z;
    const int kb   = z * KC;
    const int ke   = min(K, kb + KC);

    f32x4_t acc[4][4] = {};
    gemm_core(A, BT, K, kb, ke, row0, col0, Asl, Bsl, acc);

    const int fr = lane & 15;
    const int fq = lane >> 4;
    float* po = part + (size_t)z * M * N;
    #pragma unroll
    for (int i = 0; i < 4; ++i)
        #pragma unroll
        for (int j = 0; j < 4; ++j) {
            const int gn = col0 + wc * 64 + j * 16 + fr;
            #pragma unroll
            for (int r = 0; r < 4; ++r) {
                const int gm = row0 + wr * 64 + i * 16 + fq * 4 + r;
                po[(size_t)gm * N + gn] = acc[i][j][r];
            }
        }
}

// sum S partials + bias + act -> bf16
__global__ __launch_bounds__(256) void reduce_kernel(
    const float* __restrict__ part, const float* __restrict__ bias,
    ushort_t* __restrict__ C, int MN, int N, int S, int act)
{
    int i4 = (blockIdx.x * 256 + threadIdx.x) * 4;
    if (i4 >= MN) return;
    float4 s = *(const float4*)&part[i4];
    for (int z = 1; z < S; ++z) {
        float4 v = *(const float4*)&part[(size_t)z * MN + i4];
        s.x += v.x; s.y += v.y; s.z += v.z; s.w += v.w;
    }
    const int n = i4 % N;
    float o[4] = { s.x, s.y, s.z, s.w };
    if (bias) { o[0] += bias[n]; o[1] += bias[n+1]; o[2] += bias[n+2]; o[3] += bias[n+3]; }
    unsigned pk[2];
    ushort_t r[4];
    #pragma unroll
    for (int k = 0; k < 4; ++k) {
        float v = o[k];
        if (act == ACT_RELU)     v = fmaxf(v, 0.0f);
        else if (act == ACT_ELU) v = (v > 0.0f) ? v : (expf(v) - 1.0f);
        r[k] = f2b(v);
    }
    pk[0] = (unsigned)r[0] | ((unsigned)r[1] << 16);
    pk[1] = (unsigned)r[2] | ((unsigned)r[3] << 16);
    *(uint2*)&C[i4] = make_uint2(pk[0], pk[1]);
}

// ---------------------------------------------------------------------------
// 8-phase 256x256 split-K GEMM (T1+T2+T3+T4+T5), for big-K skinny GEMMs.
// part[z][M][N] fp32 = A[M,K] @ BT[N,K]^T over K-chunk z.
// Requirements: M%256==0, N%256==0, K%128==0.
// 512 thr (8 waves, 2Mx4N), BK=64 per LDS tile, 2 LDS buffers (128 KiB).
// LDS layout per buffer: A[256][64] bf16 @ +0, B(=BT rows)[256][64] @ +32768.
// Swizzle: 16B chunk c of row r stored at chunk c ^ (r&7)  (involution),
// realized by pre-swizzling the *global* source of global_load_lds (linear
// LDS dest, rule 21) and XOR-ing the ds_read address the same way.
// Phase schedule per iteration (tiles t=2i in buf0, t+1 in buf1):
//   ph1 (0,0): dsA[mh0]+dsB[nh0]   stage A0(t+1)->buf1
//   ph2 (0,1): dsB[nh1]            stage A1(t+1)->buf1
//   ph3 (1,0): dsA[mh1]            stage B0(t+2)->buf0
//   ph4 (1,1): -                   stage B1(t+2)->buf0   vmcnt(4)
//   ph5..ph8: same on buf1, staging A(t+2)->buf0, B(t+3)->buf1, vmcnt(4)@ph8
// Stage-issue windows are disjoint from pending ds_reads of the target
// region (A reads of a buffer complete by its (1,0) phase's lgkmcnt(0),
// B reads by its (0,1) phase's), so in-flight global_load_lds never lands
// on LDS that is still being read. vmcnt(4) leaves 2 half-tiles in flight
// across the barriers (T4: never drain to 0 in the main loop).
// ---------------------------------------------------------------------------
#define DSREAD(dst, addr) asm volatile("ds_read_b128 %0, %1" : "=v"(dst) : "v"(addr))

template <int MH>
__device__ __forceinline__ void read_A8(bf16x8_t (&av)[4][2], unsigned b0, unsigned b1)
{
    DSREAD(av[0][0], b0 + (MH * 4 + 0) * 2048);
    DSREAD(av[0][1], b1 + (MH * 4 + 0) * 2048);
    DSREAD(av[1][0], b0 + (MH * 4 + 1) * 2048);
    DSREAD(av[1][1], b1 + (MH * 4 + 1) * 2048);
    DSREAD(av[2][0], b0 + (MH * 4 + 2) * 2048);
    DSREAD(av[2][1], b1 + (MH * 4 + 2) * 2048);
    DSREAD(av[3][0], b0 + (MH * 4 + 3) * 2048);
    DSREAD(av[3][1], b1 + (MH * 4 + 3) * 2048);
}

template <int NH>
__device__ __forceinline__ void read_B8(bf16x8_t (&bvh)[2][2], unsigned b0, unsigned b1)
{
    DSREAD(bvh[0][0], b0 + (NH * 2 + 0) * 2048);
    DSREAD(bvh[0][1], b1 + (NH * 2 + 0) * 2048);
    DSREAD(bvh[1][0], b0 + (NH * 2 + 1) * 2048);
    DSREAD(bvh[1][1], b1 + (NH * 2 + 1) * 2048);
}

template <int MH, int NH>
__device__ __forceinline__ void mfma_quad(const bf16x8_t (&av)[4][2],
                                          const bf16x8_t (&bvh)[2][2],
                                          f32x4_t (&acc)[8][4])
{
    #pragma unroll
    for (int qq = 0; qq < 4; ++qq)
        #pragma unroll
        for (int pp = 0; pp < 2; ++pp)
            #pragma unroll
            for (int ss = 0; ss < 2; ++ss)
                acc[MH * 4 + qq][NH * 2 + pp] = __builtin_amdgcn_mfma_f32_16x16x32_bf16(
                    av[qq][ss], bvh[pp][ss], acc[MH * 4 + qq][NH * 2 + pp], 0, 0, 0);
}

// stage one 128-row x 64-col half-tile (2 x global_load_lds of 16B per thread)
__device__ __forceinline__ void stage_half8(
    const ushort_t* __restrict__ G, int rc0, int K, int kt,
    unsigned lo0, ushort_t* smemp, int tid)
{
    const int lane = tid & 63;
    const int ce = (((lane & 7) ^ ((lane >> 3) & 7)) << 3);   // swizzled elem col
    #pragma unroll
    for (int j = 0; j < 2; ++j) {
        const int rr = j * 64 + (tid >> 3);
        const ushort_t* g = G + (size_t)(rc0 + rr) * K + kt + ce;
        const unsigned lo = lo0 + (unsigned)((j * 64 + ((tid >> 3) & ~7)) * 128);
        __builtin_amdgcn_global_load_lds(
            (const __attribute__((address_space(1))) void*)g,
            (__attribute__((address_space(3))) void*)((char*)smemp + lo),
            16, 0, 0);
    }
}

#define PH_TAIL(MH, NH, BVH, VM) \
    __builtin_amdgcn_s_barrier(); \
    asm volatile("s_waitcnt lgkmcnt(0)"); \
    __builtin_amdgcn_sched_barrier(0); \
    __builtin_amdgcn_s_setprio(1); \
    mfma_quad<MH, NH>(av, BVH, acc); \
    __builtin_amdgcn_s_setprio(0); \
    __builtin_amdgcn_sched_barrier(0); \
    if (VM) asm volatile("s_waitcnt vmcnt(4)"); \
    __builtin_amdgcn_s_barrier();

__global__ __launch_bounds__(512, 2) void gemm_bf16_8ph_kernel(
    const ushort_t* __restrict__ A, const ushort_t* __restrict__ BT,
    float* __restrict__ part, int M, int N, int K, int IPC)
{
    extern __shared__ ushort_t smem8[];
    const int tid  = threadIdx.x;
    const int lane = tid & 63;
    const int wid  = tid >> 6;
    const int wm = wid >> 2, wn = wid & 3;
    const int fr = lane & 15, fq = lane >> 4;

    // grid decode + bijective XCD swizzle (T1, m204 form)
    const int gx = N >> 8, gy = M >> 8;
    const int nwg = (int)gridDim.x;
    const int q8 = nwg >> 3, r8 = nwg & 7;
    const int xcd = (int)blockIdx.x & 7, sub = (int)blockIdx.x >> 3;
    const int wg = (xcd < r8 ? xcd * (q8 + 1) : r8 * (q8 + 1) + (xcd - r8) * q8) + sub;
    const int bz  = wg / (gx * gy);
    const int rem = wg - bz * gx * gy;
    const int by  = rem / gx;
    const int bx  = rem - by * gx;
    const int row0 = by << 8, col0 = bx << 8;

    const int iters = K >> 7;                       // 128-K iterations total
    const int k0    = bz * IPC * 128;
    const int nit   = min(IPC, iters - bz * IPC);   // >= 1 by construction

    const unsigned SB  = (unsigned)(size_t)(__attribute__((address_space(3))) void*)smem8;
    const unsigned xa  = (unsigned)((fr & 7) << 4);
    const unsigned cs0 = ((unsigned)(fq * 16)) ^ xa;
    const unsigned cs1 = ((unsigned)(64 + fq * 16)) ^ xa;
    const unsigned arow = SB + (unsigned)((wm * 128 + fr) * 128);            // A region +0
    const unsigned brow = SB + 32768u + (unsigned)((wn * 64 + fr) * 128);    // B region +32K

    f32x4_t  acc[8][4] = {};
    bf16x8_t av[4][2];
    bf16x8_t bv[2][2][2];

    // clamp staged k-offset into the matrix (stages past the chunk end load
    // harmless garbage into buffer regions that are never read again)
    auto KT = [&](int tt) { int kt = k0 + tt * 64; return kt > K - 64 ? K - 64 : kt; };
    auto STA = [&](int tt, int h) {
        stage_half8(A, row0 + h * 128, K, KT(tt),
                    (unsigned)(((tt & 1) * 65536) + h * 16384), smem8, tid);
    };
    auto STB = [&](int tt, int h) {
        stage_half8(BT, col0 + h * 128, K, KT(tt),
                    (unsigned)(((tt & 1) * 65536) + 32768 + h * 16384), smem8, tid);
    };

    // ---- prologue: tile0 fully, tile1 B-halves; leave 2 half-tiles in flight
    STB(0, 0); STB(0, 1); STA(0, 0); STA(0, 1); STB(1, 0); STB(1, 1);
    asm volatile("s_waitcnt vmcnt(4)");
    __builtin_amdgcn_s_barrier();

    for (int it = 0; it < nit; ++it) {
        const int t = it << 1;
        // -------- phases 1-4: tile t from buf0 --------
        read_A8<0>(av, arow + cs0, arow + cs1);
        read_B8<0>(bv[0], brow + cs0, brow + cs1);
        STA(t + 1, 0);
        PH_TAIL(0, 0, bv[0], 0)

        read_B8<1>(bv[1], brow + cs0, brow + cs1);
        STA(t + 1, 1);
        PH_TAIL(0, 1, bv[1], 0)

        read_A8<1>(av, arow + cs0, arow + cs1);
        STB(t + 2, 0);
        PH_TAIL(1, 0, bv[0], 0)

        STB(t + 2, 1);
        PH_TAIL(1, 1, bv[1], 1)

        // -------- phases 5-8: tile t+1 from buf1 --------
        read_A8<0>(av, arow + 65536u + cs0, arow + 65536u + cs1);
        read_B8<0>(bv[0], brow + 65536u + cs0, brow + 65536u + cs1);
        STA(t + 2, 0);
        PH_TAIL(0, 0, bv[0], 0)

        read_B8<1>(bv[1], brow + 65536u + cs0, brow + 65536u + cs1);
        STA(t + 2, 1);
        PH_TAIL(0, 1, bv[1], 0)

        read_A8<1>(av, arow + 65536u + cs0, arow + 65536u + cs1);
        STB(t + 3, 0);
        PH_TAIL(1, 0, bv[0], 0)

        STB(t + 3, 1);
        PH_TAIL(1, 1, bv[1], 1)
    }

    // ---- epilogue: fp32 partials
    float* po = part + (size_t)bz * M * N;
    const int gmb = row0 + wm * 128 + fq * 4;
    const int gnb = col0 + wn * 64 + fr;
    #pragma unroll
    for (int mi = 0; mi < 8; ++mi)
        #pragma unroll
        for (int nj = 0; nj < 4; ++nj)
            #pragma unroll
            for (int r2 = 0; r2 < 4; ++r2)
                po[(size_t)(gmb + mi * 16 + r2) * N + (gnb + nj * 16)] = acc[mi][nj][r2];
}

// ---------------------------------------------------------------------------
// fp32 [R][Cin] (optional rowscale) -> bf16 [R][Cpad], zero-padded
// ---------------------------------------------------------------------------
__global__ __launch_bounds__(256) void cast_rows_kernel(
    const float* __restrict__ src, const float* __restrict__ rowscale,
    ushort_t* __restrict__ dst, int R, int Cin, int Cpad)
{
    int idx = blockIdx.x * 256 + threadIdx.x;
    if (idx >= R * Cpad) return;
    int r = idx / Cpad, c = idx - r * Cpad;
    float v = 0.0f;
    if (c < Cin) {
        v = src[(size_t)r * Cin + c];
        if (rowscale) v *= rowscale[r];
    }
    dst[idx] = f2b(v);
}

// ---------------------------------------------------------------------------
// fp32 W[K][N] -> bf16 WT[N][Kpad] (transpose + pad), 32x32 LDS tiles
// ---------------------------------------------------------------------------
__global__ __launch_bounds__(256) void castT_kernel(
    const float* __restrict__ W, ushort_t* __restrict__ WT,
    int K, int N, int Kpad)
{
    __shared__ float t[32][33];
    const int nb = blockIdx.x * 32, kb = blockIdx.y * 32;
    const int x = threadIdx.x & 31, y = threadIdx.x >> 5;   // 32 x 8
    #pragma unroll
    for (int yy = 0; yy < 32; yy += 8) {
        int k = kb + y + yy, n = nb + x;
        t[y + yy][x] = (k < K && n < N) ? W[(size_t)k * N + n] : 0.0f;
    }
    __syncthreads();
    #pragma unroll
    for (int yy = 0; yy < 32; yy += 8) {
        int n = nb + y + yy, kk = kb + x;
        if (n < N && kk < Kpad) WT[(size_t)n * Kpad + kk] = f2b(t[x][y + yy]);
    }
}

// ---------------------------------------------------------------------------
// monotone float<->uint encoding for atomicMax on floats
// ---------------------------------------------------------------------------
__device__ __forceinline__ unsigned enc_f(float f) {
    unsigned u = __float_as_uint(f);
    return (u >> 31) ? ~u : (u | 0x80000000u);
}
__device__ __forceinline__ float dec_f(unsigned e) {
    return (e >> 31) ? __uint_as_float(e ^ 0x80000000u) : __uint_as_float(~e);
}

// ---------------------------------------------------------------------------
// Fully fused GAT stage: attention logits + softmax + dense-A aggregation.
// One block (256 thr) per (graph, head). h bf16 [N][H*128].
//   a_s[n] = sum_c h[n][c]*a_src[c];  e = leaky(a_s[src]+a_d[dst])
//   alpha scattered into dense At[s][d];  out = elu(A @ h + bias)
// POOL=1 (GAT2): write only per-graph column max (global max pool fused).
// ---------------------------------------------------------------------------
template <int POOL>
__global__ __launch_bounds__(256) void gat_fused_kernel(
    const ushort_t* __restrict__ h, const int* __restrict__ esrc,
    const int* __restrict__ edst, const float* __restrict__ a_src,
    const float* __restrict__ a_dst, const float* __restrict__ bias,
    ushort_t* __restrict__ out, int H)
{
    const int g    = blockIdx.x / H;
    const int hd   = blockIdx.x % H;
    const int tid  = threadIdx.x;
    const int lane = tid & 63;
    const int wave = tid >> 6;
    const int base = g * NPG;
    const int HC   = H * CCH;

    __shared__ float h_l[NPG][CCH];          // 16 KB
    __shared__ float At[NPG][NPG];           // 4 KB, At[s][d]
    __shared__ float asv[CCH], adv[CCH];
    __shared__ float as_l[NPG], ad_l[NPG];
    __shared__ unsigned m_l[NPG];
    __shared__ float den_l[NPG];
    __shared__ float sc_l[EPG + NPG];
    __shared__ unsigned char s_l[EPG + NPG], d_l[EPG + NPG];
    __shared__ float ptmp[2][CCH];

    // ---- load h slice (bf16 pairs), zero At, load a-vectors ----
    {
        const int r4 = tid >> 6;             // 0..3
        const int cp = (tid & 63) * 2;       // col pair
        #pragma unroll
        for (int rr = 0; rr < NPG; rr += 4) {
            const int r = rr + r4;
            unsigned v = *(const unsigned*)(h + (size_t)(base + r) * HC + hd * CCH + cp);
            h_l[r][cp]     = b2f((ushort_t)(v & 0xffff));
            h_l[r][cp + 1] = b2f((ushort_t)(v >> 16));
        }
    }
    #pragma unroll
    for (int i = tid; i < NPG * NPG; i += 256) ((float*)At)[i] = 0.0f;
    if (tid < CCH) asv[tid] = a_src[hd * CCH + tid];
    else           adv[tid - CCH] = a_dst[hd * CCH + tid - CCH];
    if (tid < NPG) { m_l[tid] = 0u; den_l[tid] = 0.0f; }
    __syncthreads();

    // ---- attention logits per node (wave-parallel, shuffle reduce) ----
    for (int n = wave; n < NPG; n += 4) {
        float v0 = h_l[n][lane], v1 = h_l[n][lane + 64];
        float s = v0 * asv[lane] + v1 * asv[lane + 64];
        float d = v0 * adv[lane] + v1 * adv[lane + 64];
        #pragma unroll
        for (int o = 32; o > 0; o >>= 1) {
            s += __shfl_xor(s, o, 64);
            d += __shfl_xor(d, o, 64);
        }
        if (lane == 0) { as_l[n] = s; ad_l[n] = d; }
    }
    __syncthreads();

    // ---- edge scores + segment max ----
    if (tid < EPG + NPG) {
        int s, d;
        if (tid < EPG) {
            s = esrc[g * EPG + tid] - base;
            d = edst[g * EPG + tid] - base;
        } else {
            s = d = tid - EPG;               // self-loop
        }
        float e = as_l[s] + ad_l[d];
        e = (e >= 0.0f) ? e : 0.2f * e;      // leaky_relu 0.2
        sc_l[tid] = e;
        s_l[tid] = (unsigned char)s;
        d_l[tid] = (unsigned char)d;
        atomicMax(&m_l[d], enc_f(e));
    }
    __syncthreads();

    // ---- exp + segment sum ----
    if (tid < EPG + NPG) {
        float ex = expf(sc_l[tid] - dec_f(m_l[d_l[tid]]));
        sc_l[tid] = ex;
        atomicAdd(&den_l[d_l[tid]], ex);
    }
    __syncthreads();

    // ---- scatter alpha into dense At[s][d] ----
    if (tid < EPG + NPG) {
        float al = sc_l[tid] / (den_l[d_l[tid]] + 1e-16f);
        atomicAdd(&At[s_l[tid]][d_l[tid]], al);
    }
    __syncthreads();

    // ---- out[d][c] = sum_s At[s][d] * h_l[s][c]  (register-tiled) ----
    const int c    = tid & 127;
    const int half = tid >> 7;               // d range half*16 .. +16
    float acc[16] = {};
    #pragma unroll 4
    for (int s = 0; s < NPG; ++s) {
        const float hv = h_l[s][c];
        const float4* ap = (const float4*)&At[s][half * 16];
        #pragma unroll
        for (int q = 0; q < 4; ++q) {
            float4 av = ap[q];               // wave-uniform broadcast
            acc[q * 4 + 0] += av.x * hv;
            acc[q * 4 + 1] += av.y * hv;
            acc[q * 4 + 2] += av.z * hv;
            acc[q * 4 + 3] += av.w * hv;
        }
    }

    const float bb = bias[hd * CCH + c];
    if (POOL) {
        float m = -INFINITY;
        #pragma unroll
        for (int r = 0; r < 16; ++r) {
            float v = acc[r] + bb;
            v = (v > 0.0f) ? v : (expf(v) - 1.0f);
            m = fmaxf(m, v);
        }
        ptmp[half][c] = m;
        __syncthreads();
        if (tid < CCH)
            out[(size_t)g * CCH + tid] = f2b(fmaxf(ptmp[0][tid], ptmp[1][tid]));
    } else {
        #pragma unroll
        for (int r = 0; r < 16; ++r) {
            float v = acc[r] + bb;
            v = (v > 0.0f) ? v : (expf(v) - 1.0f);
            out[(size_t)(base + half * 16 + r) * HC + hd * CCH + c] = f2b(v);
        }
    }
}

// ---------------------------------------------------------------------------
// Per-row inverse L2 norm (gene branch, fp32 input)
// ---------------------------------------------------------------------------
__global__ __launch_bounds__(256) void rownorm_kernel(
    const float* __restrict__ x, float* __restrict__ inv, int K)
{
    const int row = blockIdx.x;
    const int tid = threadIdx.x;
    const float* xp = x + (size_t)row * K;
    float s = 0.f;
    for (int k = tid; k < K; k += 256) { float v = xp[k]; s += v * v; }
    __shared__ float red[256];
    red[tid] = s;
    __syncthreads();
    for (int o = 128; o > 0; o >>= 1) {
        if (tid < o) red[tid] += red[tid + o];
        __syncthreads();
    }
    if (tid == 0) inv[row] = 1.0f / fmaxf(sqrtf(red[0]), 1e-12f);
}

// ---------------------------------------------------------------------------
// Column-block copy helpers (into concat buffers)
// ---------------------------------------------------------------------------
__global__ __launch_bounds__(256) void copyb_kernel(
    ushort_t* __restrict__ dst, int ld, int off,
    const ushort_t* __restrict__ src, int rows, int cols)
{
    int idx = blockIdx.x * 256 + threadIdx.x;
    if (idx >= rows * cols) return;
    int r = idx / cols, c = idx - r * cols;
    dst[(size_t)r * ld + off + c] = src[idx];
}

__global__ __launch_bounds__(256) void castcols_kernel(
    ushort_t* __restrict__ dst, int ld, int off,
    const float* __restrict__ src, int rows, int cols)
{
    int idx = blockIdx.x * 256 + threadIdx.x;
    if (idx >= rows * cols) return;
    int r = idx / cols, c = idx - r * cols;
    dst[(size_t)r * ld + off + c] = f2b(src[idx]);
}

// ---------------------------------------------------------------------------
// Final N_TASKS=1: out[b] = y[b,:256] . w + bout   (y bf16)
// ---------------------------------------------------------------------------
__global__ __launch_bounds__(256) void final_kernel(
    const ushort_t* __restrict__ y, const float* __restrict__ w,
    const float* __restrict__ b, float* __restrict__ out)
{
    const int row = blockIdx.x;
    const int tid = threadIdx.x;
    float v = b2f(y[(size_t)row * 256 + tid]) * w[tid];
    __shared__ float red[256];
    red[tid] = v;
    __syncthreads();
    for (int o = 128; o > 0; o >>= 1) {
        if (tid < o) red[tid] += red[tid + o];
        __syncthreads();
    }
    if (tid == 0) out[row] = red[0] + b[0];
}

// ---------------------------------------------------------------------------
// Host side
// ---------------------------------------------------------------------------
static inline void launch_gemm(const ushort_t* A, const ushort_t* BT,
                               const float* bias, ushort_t* C,
                               int M, int N, int K, int act, hipStream_t stream)
{
    dim3 grid(N / GBN, M / GBM);
    gemm_bf16_kernel<<<grid, 256, 0, stream>>>(A, BT, bias, C, M, N, K, act);
}

// split-K GEMM: partials into `part` (fp32), then reduce with bias+act
static inline void launch_gemm_sk(const ushort_t* A, const ushort_t* BT,
                                  const float* bias, ushort_t* C, float* part,
                                  int M, int N, int K, int S, int act,
                                  hipStream_t stream)
{
    if (S <= 1) { launch_gemm(A, BT, bias, C, M, N, K, act, stream); return; }
    const int iters = K / GBK;
    const int ipc   = (iters + S - 1) / S;         // iters per chunk
    const int S_eff = (iters + ipc - 1) / ipc;     // no empty chunks
    const int KC    = ipc * GBK;
    dim3 grid(N / GBN, M / GBM, S_eff);
    gemm_bf16_part_kernel<<<grid, 256, 0, stream>>>(A, BT, part, M, N, K, KC);
    const int MN = M * N;
    reduce_kernel<<<(MN / 4 + 255) / 256, 256, 0, stream>>>(
        part, bias, C, MN, N, S_eff, act);
}

// 8-phase 256^2 split-K GEMM path (M%256==0, N%256==0, K%128==0)
static inline void launch_gemm_8ph(const ushort_t* A, const ushort_t* BT,
                                   const float* bias, ushort_t* C, float* part,
                                   int M, int N, int K, int S, int act,
                                   hipStream_t stream)
{
    const int iters = K >> 7;                      // 128-K iterations
    const int ipc   = (iters + S - 1) / S;
    const int S_eff = (iters + ipc - 1) / ipc;
    const int gx = N >> 8, gy = M >> 8;
    const int nwg = gx * gy * S_eff;
    static bool attr_done = false;
    if (!attr_done) {
        (void)hipFuncSetAttribute((const void*)gemm_bf16_8ph_kernel,
                                  hipFuncAttributeMaxDynamicSharedMemorySize, 131072);
        attr_done = true;
    }
    gemm_bf16_8ph_kernel<<<dim3(nwg), 512, 131072, stream>>>(A, BT, part, M, N, K, ipc);
    const int MN = M * N;
    reduce_kernel<<<(MN / 4 + 255) / 256, 256, 0, stream>>>(
        part, bias, C, MN, N, S_eff, act);
}

static inline void launch_castT(const float* W, ushort_t* WT, int K, int N,
                                int Kpad, hipStream_t stream)
{
    dim3 grid((N + 31) / 32, (Kpad + 31) / 32);
    castT_kernel<<<grid, 256, 0, stream>>>(W, WT, K, N, Kpad);
}

extern "C" void kernel_launch(void* const* d_in, const int* in_sizes, int n_in,
                              void* d_out, int out_size, void* d_ws, size_t ws_size,
                              hipStream_t stream)
{
    const float* x1      = (const float*)d_in[0];
    const float* x2      = (const float*)d_in[1];
    const float* gene    = (const float*)d_in[2];
    const float* drr     = (const float*)d_in[3];
    const float* drc     = (const float*)d_in[4];
    const float* prot    = (const float*)d_in[5];
    const int*   ei1     = (const int*)d_in[6];
    const int*   ei2     = (const int*)d_in[7];
    const float* W_gat1  = (const float*)d_in[9];
    const float* b_gat1  = (const float*)d_in[10];
    const float* a_src1  = (const float*)d_in[11];
    const float* a_dst1  = (const float*)d_in[12];
    const float* W_gat2  = (const float*)d_in[13];
    const float* b_gat2  = (const float*)d_in[14];
    const float* a_src2  = (const float*)d_in[15];
    const float* a_dst2  = (const float*)d_in[16];
    const float* W_fcg   = (const float*)d_in[17];
    const float* b_fcg   = (const float*)d_in[18];
    const float* Wr1     = (const float*)d_in[19];
    const float* br1     = (const float*)d_in[20];
    const float* Wr2     = (const float*)d_in[21];
    const float* br2     = (const float*)d_in[22];
    const float* Wr3     = (const float*)d_in[23];
    const float* br3     = (const float*)d_in[24];
    const float* Wp1     = (const float*)d_in[25];
    const float* bp1     = (const float*)d_in[26];
    const float* Wp2     = (const float*)d_in[27];
    const float* bp2     = (const float*)d_in[28];
    const float* Wp3     = (const float*)d_in[29];
    const float* bp3     = (const float*)d_in[30];
    const float* Wdrr    = (const float*)d_in[31];
    const float* bdrr    = (const float*)d_in[32];
    const float* Wdrc    = (const float*)d_in[33];
    const float* bdrc    = (const float*)d_in[34];
    const float* Wf1     = (const float*)d_in[35];
    const float* bf1     = (const float*)d_in[36];
    const float* Wf2     = (const float*)d_in[37];
    const float* bf2     = (const float*)d_in[38];
    const float* Wout    = (const float*)d_in[39];
    const float* bout    = (const float*)d_in[40];
    float* outp = (float*)d_out;

    char* ws = (char*)d_ws;
    size_t off = 0;
    auto alloc = [&](size_t bytes) -> char* {
        char* r = ws + off;
        off += (bytes + 255) & ~(size_t)255;
        return r;
    };

    // Phase-overlaid big regions:
    // BIG0 (134 MB): drug phase = go1_full [65536x1024 bf16]
    //                MLP phase  = WT_r1 + gene_nb + cell1 + WT_r2 + WT_p2 + WT_p1
    // BIG1 (67 MB):  drug phase = h1 [32768x1024 bf16] (per-drug, reused)
    //                MLP phase  = split-K fp32 partial buffer (max 67 MB, gene S=8)
    char* BIG0 = alloc(134217728);
    char* BIG1 = alloc(67108864);

    ushort_t* go1f   = (ushort_t*)BIG0;
    ushort_t* h1     = (ushort_t*)BIG1;
    float*    part   = (float*)BIG1;
    ushort_t* WT_r1  = (ushort_t*)(BIG0 + 0);           // 2048x18048 = 73,924,608
    ushort_t* gene_nb= (ushort_t*)(BIG0 + 73924608);    // 1024x18048 = 36,962,304
    ushort_t* cell1  = (ushort_t*)(BIG0 + 110886912);   // 1024x2048  =  4,194,304
    ushort_t* WT_r2  = (ushort_t*)(BIG0 + 115081216);   // 512x2048   =  2,097,152
    ushort_t* WT_p2  = (ushort_t*)(BIG0 + 117178368);   // 512x1024   =  1,048,576
    ushort_t* WT_p1  = (ushort_t*)(BIG0 + 118226944);   // 1024x6784  = 13,895,680 -> 132,122,624

    ushort_t* xb     = (ushort_t*)alloc((size_t)NNODES * 96 * 2);        // per-drug
    char*     h2reg  = alloc((size_t)2 * NNODES * 128 * 2);              // 16.8 MB
    char*     catreg = alloc((size_t)2 * 1024 * 2176 * 2);               //  8.9 MB
    ushort_t* h2f    = (ushort_t*)h2reg;     // drug phase
    ushort_t* protb  = (ushort_t*)h2reg;     // MLP phase alias (13.9 MB <= 16.8)
    ushort_t* cat1   = (ushort_t*)catreg;
    ushort_t* cat2   = (ushort_t*)(catreg + (size_t)1024 * 2176 * 2);
    ushort_t* pooled = (ushort_t*)alloc((size_t)2 * BATCH * 128 * 2);
    ushort_t* gpair  = (ushort_t*)alloc((size_t)2 * BATCH * 128 * 2);
    float*    invn   = (float*)alloc((size_t)BATCH * 4);
    ushort_t* cvec   = (ushort_t*)alloc((size_t)BATCH * 256 * 2);
    ushort_t* pvec   = (ushort_t*)alloc((size_t)BATCH * 256 * 2);
    ushort_t* y1     = (ushort_t*)alloc((size_t)BATCH * 512 * 2);
    ushort_t* y2     = (ushort_t*)alloc((size_t)BATCH * 256 * 2);
    ushort_t* WT_g1  = (ushort_t*)alloc((size_t)1024 * 96 * 2);
    ushort_t* WT_g2  = (ushort_t*)alloc((size_t)128 * 1024 * 2);
    ushort_t* WT_fcg = (ushort_t*)alloc((size_t)128 * 128 * 2);
    ushort_t* WT_r3  = (ushort_t*)alloc((size_t)256 * 512 * 2);
    ushort_t* WT_p3  = (ushort_t*)alloc((size_t)256 * 512 * 2);
    ushort_t* WT_f2  = (ushort_t*)alloc((size_t)256 * 512 * 2);
    ushort_t* WT_drr = (ushort_t*)alloc((size_t)2176 * 2176 * 2);
    ushort_t* WT_drc = (ushort_t*)alloc((size_t)2176 * 2176 * 2);
    ushort_t* WT_f1  = (ushort_t*)alloc((size_t)512 * 4864 * 2);
    ushort_t* p1b    = (ushort_t*)alloc((size_t)1024 * 1024 * 2);
    ushort_t* p2b    = (ushort_t*)alloc((size_t)1024 * 512 * 2);
    ushort_t* cell2  = (ushort_t*)alloc((size_t)1024 * 512 * 2);
    ushort_t* d1     = (ushort_t*)alloc((size_t)1024 * 2176 * 2);
    ushort_t* d2     = (ushort_t*)alloc((size_t)1024 * 2176 * 2);
    ushort_t* ybuf   = (ushort_t*)alloc((size_t)1024 * 4864 * 2);

    const int E = in_sizes[6] / 2;   // 131072

    // ---------------- drug-phase weight casts ----------------
    launch_castT(W_gat1, WT_g1, INFEAT, 1024, 96, stream);
    launch_castT(W_gat2, WT_g2, 1024, 128, 1024, stream);
    launch_castT(W_fcg,  WT_fcg, 128, 128, 128, stream);

    // ---------------- drug branch: GAT1 per drug, write into shared go1f ---
    for (int drug = 0; drug < 2; drug++) {
        const float* x  = drug ? x2 : x1;
        const int*   es = (drug ? ei2 : ei1);
        const int*   ed = es + E;
        ushort_t* go1d = go1f + (size_t)drug * NNODES * 1024;

        cast_rows_kernel<<<(NNODES * 96 + 255) / 256, 256, 0, stream>>>(
            x, nullptr, xb, NNODES, INFEAT, 96);
        launch_gemm(xb, WT_g1, nullptr, h1, NNODES, 1024, 96, ACT_NONE, stream);
        gat_fused_kernel<0><<<BATCH * NHEAD, 256, 0, stream>>>(
            h1, es, ed, a_src1, a_dst1, b_gat1, go1d, NHEAD);
    }

    // ---------------- batched GAT2 GEMM (M=65536 -> 512 blocks) ------------
    launch_gemm(go1f, WT_g2, nullptr, h2f, 2 * NNODES, 128, 1024, ACT_NONE, stream);

    // BIG0 (go1f) now dead -> cast MLP-phase weights into it
    launch_castT(Wr1, WT_r1, GENE, 2048, GENEP, stream);
    launch_castT(Wr2, WT_r2, 2048, 512, 2048, stream);
    launch_castT(Wp1, WT_p1, PROT, 1024, PROTP, stream);
    launch_castT(Wp2, WT_p2, 1024, 512, 1024, stream);
    launch_castT(Wr3, WT_r3, 512, 256, 512, stream);
    launch_castT(Wp3, WT_p3, 512, 256, 512, stream);
    launch_castT(Wf2, WT_f2, 512, 256, 512, stream);
    launch_castT(Wdrr, WT_drr, 2176, 2176, 2176, stream);
    launch_castT(Wdrc, WT_drc, 2176, 2176, 2176, stream);
    launch_castT(Wf1, WT_f1, 4864, 512, 4864, stream);

    // ---------------- GAT2 fused (attn + softmax + agg + maxpool) ----------
    for (int drug = 0; drug < 2; drug++) {
        const int* es = (drug ? ei2 : ei1);
        const int* ed = es + E;
        gat_fused_kernel<1><<<BATCH, 256, 0, stream>>>(
            h2f + (size_t)drug * NNODES * 128, es, ed,
            a_src2, a_dst2, b_gat2, pooled + (size_t)drug * BATCH * 128, 1);
    }
    launch_gemm(pooled, WT_fcg, b_fcg, gpair, 2 * BATCH, 128, 128, ACT_RELU, stream);
    // gpair rows [0,1024) = g1, [1024,2048) = g2

    // ---------------- gene branch (8-phase split-K for the big-K GEMM) -----
    rownorm_kernel<<<BATCH, 256, 0, stream>>>(gene, invn, GENE);
    cast_rows_kernel<<<(BATCH * GENEP + 255) / 256, 256, 0, stream>>>(
        gene, invn, gene_nb, BATCH, GENE, GENEP);
    launch_gemm_8ph(gene_nb, WT_r1, br1, cell1, part, BATCH, 2048, GENEP, 8, ACT_RELU, stream);
    launch_gemm_sk(cell1, WT_r2, br2, cell2, part, BATCH, 512, 2048, 8, ACT_RELU, stream);
    launch_gemm_sk(cell2, WT_r3, br3, cvec, part, BATCH, 256, 512, 4, ACT_RELU, stream);

    // ---------------- protein branch (8-phase for K=6784; protb aliases h2f)
    cast_rows_kernel<<<(BATCH * PROTP + 255) / 256, 256, 0, stream>>>(
        prot, nullptr, protb, BATCH, PROT, PROTP);
    launch_gemm_8ph(protb, WT_p1, bp1, p1b, part, BATCH, 1024, PROTP, 16, ACT_ELU, stream);
    launch_gemm_sk(p1b, WT_p2, bp2, p2b, part, BATCH, 512, 1024, 4, ACT_ELU, stream);
    launch_gemm_sk(p2b, WT_p3, bp3, pvec, part, BATCH, 256, 512, 4, ACT_RELU, stream);

    // ---------------- fingerprint fusion ----------------
    {
        int n = BATCH * CCH;
        copyb_kernel<<<(n + 255) / 256, 256, 0, stream>>>(cat1, 2176, 0, gpair, BATCH, CCH);
        copyb_kernel<<<(n + 255) / 256, 256, 0, stream>>>(cat2, 2176, 0, gpair + BATCH * CCH, BATCH, CCH);
        n = BATCH * FPD;
        castcols_kernel<<<(n + 255) / 256, 256, 0, stream>>>(cat1, 2176, CCH, drr, BATCH, FPD);
        castcols_kernel<<<(n + 255) / 256, 256, 0, stream>>>(cat2, 2176, CCH, drc, BATCH, FPD);
    }
    launch_gemm_sk(cat1, WT_drr, bdrr, d1, part, BATCH, 2176, 2176, 4, ACT_RELU, stream);
    launch_gemm_sk(cat2, WT_drc, bdrc, d2, part, BATCH, 2176, 2176, 4, ACT_RELU, stream);

    // ---------------- concat + predictor ----------------
    {
        int n = BATCH * 2176;
        copyb_kernel<<<(n + 255) / 256, 256, 0, stream>>>(ybuf, 4864, 0,    d1, BATCH, 2176);
        copyb_kernel<<<(n + 255) / 256, 256, 0, stream>>>(ybuf, 4864, 2176, d2, BATCH, 2176);
        n = BATCH * 256;
        copyb_kernel<<<(n + 255) / 256, 256, 0, stream>>>(ybuf, 4864, 4352, cvec, BATCH, 256);
        copyb_kernel<<<(n + 255) / 256, 256, 0, stream>>>(ybuf, 4864, 4608, pvec, BATCH, 256);
    }
    launch_gemm_sk(ybuf, WT_f1, bf1, y1, part, BATCH, 512, 4864, 8, ACT_RELU, stream);
    launch_gemm_sk(y1, WT_f2, bf2, y2, part, BATCH, 256, 512, 4, ACT_RELU, stream);
    final_kernel<<<BATCH, 256, 0, stream>>>(y2, Wout, bout, outp);
}

// Round 2
// 1134.233 us; speedup vs baseline: 1.1077x; 1.0475x over previous
//
#include <hip/hip_runtime.h>
#include <math.h>

// ---------------------------------------------------------------------------
// Model dims (fixed by the reference)
// ---------------------------------------------------------------------------
#define BATCH   1024
#define NPG     32
#define NNODES  (BATCH * NPG)      // 32768 per drug
#define EPG     128
#define INFEAT  78
#define CCH     128
#define NHEAD   8
#define GENE    18000
#define GENEP   18048              // padded to %128 (8-phase kernel needs K%128)
#define PROT    6688
#define PROTP   6784               // padded to %128
#define FPD     2048

#define ACT_NONE 0
#define ACT_RELU 1
#define ACT_ELU  2

typedef unsigned short ushort_t;
typedef __bf16 bf16x8_t __attribute__((ext_vector_type(8)));
typedef float  f32x4_t  __attribute__((ext_vector_type(4)));

__device__ __forceinline__ float b2f(ushort_t u) {
    return __uint_as_float(((unsigned)u) << 16);
}
__device__ __forceinline__ ushort_t f2b(float f) {
    unsigned x = __float_as_uint(f);
    return (ushort_t)((x + 0x7fffu + ((x >> 16) & 1u)) >> 16);   // RNE
}

// ---------------------------------------------------------------------------
// bf16 MFMA GEMM (m97 structure): C[M,N] = act(A[M,K] @ BT[N,K]^T + bias)
// A, BT bf16 (K%32==0); C bf16; bias fp32. M%128==0, N%128==0.
// 128x128 tile, BK=32, 256 threads (2x2 waves of 64x64), global_load_lds.
// ---------------------------------------------------------------------------
#define GBM 128
#define GBN 128
#define GBK 32

__device__ __forceinline__ void gemm_core(
    const ushort_t* __restrict__ A, const ushort_t* __restrict__ BT,
    int K, int kb, int ke, int row0, int col0,
    ushort_t* Asl, ushort_t* Bsl, f32x4_t acc[4][4])
{
    const int tid  = threadIdx.x;
    const int wave = tid >> 6;
    const int lane = tid & 63;
    const int wr   = wave >> 1;
    const int wc   = wave & 1;
    const int srow = lane >> 2;        // 0..15
    const int skel = (lane & 3) * 8;   // bf16 elem offset

    for (int k0 = kb; k0 < ke; k0 += GBK) {
        __syncthreads();               // protect LDS from previous iteration
        #pragma unroll
        for (int t = 0; t < 2; ++t) {
            const int rg = wave * 32 + t * 16;                   // wave-uniform
            const ushort_t* ga = A + (size_t)(row0 + rg + srow) * K + k0 + skel;
            __builtin_amdgcn_global_load_lds(
                (const __attribute__((address_space(1))) void*)ga,
                (__attribute__((address_space(3))) void*)&Asl[rg * GBK], 16, 0, 0);
            const ushort_t* gb = BT + (size_t)(col0 + rg + srow) * K + k0 + skel;
            __builtin_amdgcn_global_load_lds(
                (const __attribute__((address_space(1))) void*)gb,
                (__attribute__((address_space(3))) void*)&Bsl[rg * GBK], 16, 0, 0);
        }
        __syncthreads();

        const int fr = lane & 15;
        const int fq = lane >> 4;
        bf16x8_t av[4], bv[4];
        #pragma unroll
        for (int i = 0; i < 4; ++i)
            av[i] = *(const bf16x8_t*)&Asl[(wr * 64 + i * 16 + fr) * GBK + fq * 8];
        #pragma unroll
        for (int j = 0; j < 4; ++j)
            bv[j] = *(const bf16x8_t*)&Bsl[(wc * 64 + j * 16 + fr) * GBK + fq * 8];
        #pragma unroll
        for (int i = 0; i < 4; ++i)
            #pragma unroll
            for (int j = 0; j < 4; ++j)
                acc[i][j] = __builtin_amdgcn_mfma_f32_16x16x32_bf16(
                    av[i], bv[j], acc[i][j], 0, 0, 0);
    }
}

__global__ __launch_bounds__(256) void gemm_bf16_kernel(
    const ushort_t* __restrict__ A, const ushort_t* __restrict__ BT,
    const float* __restrict__ bias, ushort_t* __restrict__ C,
    int M, int N, int K, int act)
{
    __shared__ ushort_t Asl[GBM * GBK];
    __shared__ ushort_t Bsl[GBN * GBK];
    const int lane = threadIdx.x & 63;
    const int wave = threadIdx.x >> 6;
    const int wr = wave >> 1, wc = wave & 1;
    const int row0 = blockIdx.y * GBM;
    const int col0 = blockIdx.x * GBN;

    f32x4_t acc[4][4] = {};
    gemm_core(A, BT, K, 0, K, row0, col0, Asl, Bsl, acc);

    const int fr = lane & 15;
    const int fq = lane >> 4;
    #pragma unroll
    for (int i = 0; i < 4; ++i) {
        #pragma unroll
        for (int j = 0; j < 4; ++j) {
            const int gn = col0 + wc * 64 + j * 16 + fr;
            const float bb = bias ? bias[gn] : 0.0f;
            #pragma unroll
            for (int r = 0; r < 4; ++r) {
                const int gm = row0 + wr * 64 + i * 16 + fq * 4 + r;
                float v = acc[i][j][r] + bb;
                if (act == ACT_RELU)     v = fmaxf(v, 0.0f);
                else if (act == ACT_ELU) v = (v > 0.0f) ? v : (expf(v) - 1.0f);
                C[(size_t)gm * N + gn] = f2b(v);
            }
        }
    }
}

// split-K variant: grid.z = chunk index, fp32 partials out (no bias/act)
__global__ __launch_bounds__(256) void gemm_bf16_part_kernel(
    const ushort_t* __restrict__ A, const ushort_t* __restrict__ BT,
    float* __restrict__ part, int M, int N, int K, int KC)
{
    __shared__ ushort_t Asl[GBM * GBK];
    __shared__ ushort_t Bsl[GBN * GBK];
    const int lane = threadIdx.x & 63;
    const int wave = threadIdx.x >> 6;
    const int wr = wave >> 1, wc = wave & 1;
    const int row0 = blockIdx.y * GBM;
    const int col0 = blockIdx.x * GBN;
    const int z    = blockIdx.z;
    const int kb   = z * KC;
    const int ke   = min(K, kb + KC);

    f32x4_t acc[4][4] = {};
    gemm_core(A, BT, K, kb, ke, row0, col0, Asl, Bsl, acc);

    const int fr = lane & 15;
    const int fq = lane >> 4;
    float* po = part + (size_t)z * M * N;
    #pragma unroll
    for (int i = 0; i < 4; ++i)
        #pragma unroll
        for (int j = 0; j < 4; ++j) {
            const int gn = col0 + wc * 64 + j * 16 + fr;
            #pragma unroll
            for (int r = 0; r < 4; ++r) {
                const int gm = row0 + wr * 64 + i * 16 + fq * 4 + r;
                po[(size_t)gm * N + gn] = acc[i][j][r];
            }
        }
}

// sum S partials + bias + act -> bf16
__global__ __launch_bounds__(256) void reduce_kernel(
    const float* __restrict__ part, const float* __restrict__ bias,
    ushort_t* __restrict__ C, int MN, int N, int S, int act)
{
    int i4 = (blockIdx.x * 256 + threadIdx.x) * 4;
    if (i4 >= MN) return;
    float4 s = *(const float4*)&part[i4];
    for (int z = 1; z < S; ++z) {
        float4 v = *(const float4*)&part[(size_t)z * MN + i4];
        s.x += v.x; s.y += v.y; s.z += v.z; s.w += v.w;
    }
    const int n = i4 % N;
    float o[4] = { s.x, s.y, s.z, s.w };
    if (bias) { o[0] += bias[n]; o[1] += bias[n+1]; o[2] += bias[n+2]; o[3] += bias[n+3]; }
    unsigned pk[2];
    ushort_t r[4];
    #pragma unroll
    for (int k = 0; k < 4; ++k) {
        float v = o[k];
        if (act == ACT_RELU)     v = fmaxf(v, 0.0f);
        else if (act == ACT_ELU) v = (v > 0.0f) ? v : (expf(v) - 1.0f);
        r[k] = f2b(v);
    }
    pk[0] = (unsigned)r[0] | ((unsigned)r[1] << 16);
    pk[1] = (unsigned)r[2] | ((unsigned)r[3] << 16);
    *(uint2*)&C[i4] = make_uint2(pk[0], pk[1]);
}

// ---------------------------------------------------------------------------
// 8-phase 256x256 split-K GEMM (T1+T2+T3+T4+T5), for big-K skinny GEMMs.
// part[z][M][N] fp32 = A[M,K] @ BT[N,K]^T over K-chunk z.
// Requirements: M%256==0, N%256==0, K%128==0.
// ---------------------------------------------------------------------------
#define DSREAD(dst, addr) asm volatile("ds_read_b128 %0, %1" : "=v"(dst) : "v"(addr))

template <int MH>
__device__ __forceinline__ void read_A8(bf16x8_t (&av)[4][2], unsigned b0, unsigned b1)
{
    DSREAD(av[0][0], b0 + (MH * 4 + 0) * 2048);
    DSREAD(av[0][1], b1 + (MH * 4 + 0) * 2048);
    DSREAD(av[1][0], b0 + (MH * 4 + 1) * 2048);
    DSREAD(av[1][1], b1 + (MH * 4 + 1) * 2048);
    DSREAD(av[2][0], b0 + (MH * 4 + 2) * 2048);
    DSREAD(av[2][1], b1 + (MH * 4 + 2) * 2048);
    DSREAD(av[3][0], b0 + (MH * 4 + 3) * 2048);
    DSREAD(av[3][1], b1 + (MH * 4 + 3) * 2048);
}

template <int NH>
__device__ __forceinline__ void read_B8(bf16x8_t (&bvh)[2][2], unsigned b0, unsigned b1)
{
    DSREAD(bvh[0][0], b0 + (NH * 2 + 0) * 2048);
    DSREAD(bvh[0][1], b1 + (NH * 2 + 0) * 2048);
    DSREAD(bvh[1][0], b0 + (NH * 2 + 1) * 2048);
    DSREAD(bvh[1][1], b1 + (NH * 2 + 1) * 2048);
}

template <int MH, int NH>
__device__ __forceinline__ void mfma_quad(const bf16x8_t (&av)[4][2],
                                          const bf16x8_t (&bvh)[2][2],
                                          f32x4_t (&acc)[8][4])
{
    #pragma unroll
    for (int qq = 0; qq < 4; ++qq)
        #pragma unroll
        for (int pp = 0; pp < 2; ++pp)
            #pragma unroll
            for (int ss = 0; ss < 2; ++ss)
                acc[MH * 4 + qq][NH * 2 + pp] = __builtin_amdgcn_mfma_f32_16x16x32_bf16(
                    av[qq][ss], bvh[pp][ss], acc[MH * 4 + qq][NH * 2 + pp], 0, 0, 0);
}

// stage one 128-row x 64-col half-tile (2 x global_load_lds of 16B per thread)
__device__ __forceinline__ void stage_half8(
    const ushort_t* __restrict__ G, int rc0, int K, int kt,
    unsigned lo0, ushort_t* smemp, int tid)
{
    const int lane = tid & 63;
    const int ce = (((lane & 7) ^ ((lane >> 3) & 7)) << 3);   // swizzled elem col
    #pragma unroll
    for (int j = 0; j < 2; ++j) {
        const int rr = j * 64 + (tid >> 3);
        const ushort_t* g = G + (size_t)(rc0 + rr) * K + kt + ce;
        const unsigned lo = lo0 + (unsigned)((j * 64 + ((tid >> 3) & ~7)) * 128);
        __builtin_amdgcn_global_load_lds(
            (const __attribute__((address_space(1))) void*)g,
            (__attribute__((address_space(3))) void*)((char*)smemp + lo),
            16, 0, 0);
    }
}

#define PH_TAIL(MH, NH, BVH, VM) \
    __builtin_amdgcn_s_barrier(); \
    asm volatile("s_waitcnt lgkmcnt(0)"); \
    __builtin_amdgcn_sched_barrier(0); \
    __builtin_amdgcn_s_setprio(1); \
    mfma_quad<MH, NH>(av, BVH, acc); \
    __builtin_amdgcn_s_setprio(0); \
    __builtin_amdgcn_sched_barrier(0); \
    if (VM) asm volatile("s_waitcnt vmcnt(4)"); \
    __builtin_amdgcn_s_barrier();

__global__ __launch_bounds__(512, 2) void gemm_bf16_8ph_kernel(
    const ushort_t* __restrict__ A, const ushort_t* __restrict__ BT,
    float* __restrict__ part, int M, int N, int K, int IPC)
{
    extern __shared__ ushort_t smem8[];
    const int tid  = threadIdx.x;
    const int lane = tid & 63;
    const int wid  = tid >> 6;
    const int wm = wid >> 2, wn = wid & 3;
    const int fr = lane & 15, fq = lane >> 4;

    // grid decode + bijective XCD swizzle (T1, m204 form)
    const int gx = N >> 8, gy = M >> 8;
    const int nwg = (int)gridDim.x;
    const int q8 = nwg >> 3, r8 = nwg & 7;
    const int xcd = (int)blockIdx.x & 7, sub = (int)blockIdx.x >> 3;
    const int wg = (xcd < r8 ? xcd * (q8 + 1) : r8 * (q8 + 1) + (xcd - r8) * q8) + sub;
    const int bz  = wg / (gx * gy);
    const int rem = wg - bz * gx * gy;
    const int by  = rem / gx;
    const int bx  = rem - by * gx;
    const int row0 = by << 8, col0 = bx << 8;

    const int iters = K >> 7;                       // 128-K iterations total
    const int k0    = bz * IPC * 128;
    const int nit   = min(IPC, iters - bz * IPC);   // >= 1 by construction

    const unsigned SB  = (unsigned)(size_t)(__attribute__((address_space(3))) void*)smem8;
    const unsigned xa  = (unsigned)((fr & 7) << 4);
    const unsigned cs0 = ((unsigned)(fq * 16)) ^ xa;
    const unsigned cs1 = ((unsigned)(64 + fq * 16)) ^ xa;
    const unsigned arow = SB + (unsigned)((wm * 128 + fr) * 128);            // A region +0
    const unsigned brow = SB + 32768u + (unsigned)((wn * 64 + fr) * 128);    // B region +32K

    f32x4_t  acc[8][4] = {};
    bf16x8_t av[4][2];
    bf16x8_t bv[2][2][2];

    auto KT = [&](int tt) { int kt = k0 + tt * 64; return kt > K - 64 ? K - 64 : kt; };
    auto STA = [&](int tt, int h) {
        stage_half8(A, row0 + h * 128, K, KT(tt),
                    (unsigned)(((tt & 1) * 65536) + h * 16384), smem8, tid);
    };
    auto STB = [&](int tt, int h) {
        stage_half8(BT, col0 + h * 128, K, KT(tt),
                    (unsigned)(((tt & 1) * 65536) + 32768 + h * 16384), smem8, tid);
    };

    // ---- prologue: tile0 fully, tile1 B-halves; leave 2 half-tiles in flight
    STB(0, 0); STB(0, 1); STA(0, 0); STA(0, 1); STB(1, 0); STB(1, 1);
    asm volatile("s_waitcnt vmcnt(4)");
    __builtin_amdgcn_s_barrier();

    for (int it = 0; it < nit; ++it) {
        const int t = it << 1;
        // -------- phases 1-4: tile t from buf0 --------
        read_A8<0>(av, arow + cs0, arow + cs1);
        read_B8<0>(bv[0], brow + cs0, brow + cs1);
        STA(t + 1, 0);
        PH_TAIL(0, 0, bv[0], 0)

        read_B8<1>(bv[1], brow + cs0, brow + cs1);
        STA(t + 1, 1);
        PH_TAIL(0, 1, bv[1], 0)

        read_A8<1>(av, arow + cs0, arow + cs1);
        STB(t + 2, 0);
        PH_TAIL(1, 0, bv[0], 0)

        STB(t + 2, 1);
        PH_TAIL(1, 1, bv[1], 1)

        // -------- phases 5-8: tile t+1 from buf1 --------
        read_A8<0>(av, arow + 65536u + cs0, arow + 65536u + cs1);
        read_B8<0>(bv[0], brow + 65536u + cs0, brow + 65536u + cs1);
        STA(t + 2, 0);
        PH_TAIL(0, 0, bv[0], 0)

        read_B8<1>(bv[1], brow + 65536u + cs0, brow + 65536u + cs1);
        STA(t + 2, 1);
        PH_TAIL(0, 1, bv[1], 0)

        read_A8<1>(av, arow + 65536u + cs0, arow + 65536u + cs1);
        STB(t + 3, 0);
        PH_TAIL(1, 0, bv[0], 0)

        STB(t + 3, 1);
        PH_TAIL(1, 1, bv[1], 1)
    }

    // ---- epilogue: fp32 partials
    float* po = part + (size_t)bz * M * N;
    const int gmb = row0 + wm * 128 + fq * 4;
    const int gnb = col0 + wn * 64 + fr;
    #pragma unroll
    for (int mi = 0; mi < 8; ++mi)
        #pragma unroll
        for (int nj = 0; nj < 4; ++nj)
            #pragma unroll
            for (int r2 = 0; r2 < 4; ++r2)
                po[(size_t)(gmb + mi * 16 + r2) * N + (gnb + nj * 16)] = acc[mi][nj][r2];
}

// ---------------------------------------------------------------------------
// fp32 [R][Cin] (optional rowscale) -> bf16 [R][Cpad], zero-padded
// ---------------------------------------------------------------------------
__global__ __launch_bounds__(256) void cast_rows_kernel(
    const float* __restrict__ src, const float* __restrict__ rowscale,
    ushort_t* __restrict__ dst, int R, int Cin, int Cpad)
{
    int idx = blockIdx.x * 256 + threadIdx.x;
    if (idx >= R * Cpad) return;
    int r = idx / Cpad, c = idx - r * Cpad;
    float v = 0.0f;
    if (c < Cin) {
        v = src[(size_t)r * Cin + c];
        if (rowscale) v *= rowscale[r];
    }
    dst[idx] = f2b(v);
}

// ---------------------------------------------------------------------------
// fp32 W[K][N] -> bf16 WT[N][Kpad] (transpose + pad), 32x32 LDS tiles
// ---------------------------------------------------------------------------
__global__ __launch_bounds__(256) void castT_kernel(
    const float* __restrict__ W, ushort_t* __restrict__ WT,
    int K, int N, int Kpad)
{
    __shared__ float t[32][33];
    const int nb = blockIdx.x * 32, kb = blockIdx.y * 32;
    const int x = threadIdx.x & 31, y = threadIdx.x >> 5;   // 32 x 8
    #pragma unroll
    for (int yy = 0; yy < 32; yy += 8) {
        int k = kb + y + yy, n = nb + x;
        t[y + yy][x] = (k < K && n < N) ? W[(size_t)k * N + n] : 0.0f;
    }
    __syncthreads();
    #pragma unroll
    for (int yy = 0; yy < 32; yy += 8) {
        int n = nb + y + yy, kk = kb + x;
        if (n < N && kk < Kpad) WT[(size_t)n * Kpad + kk] = f2b(t[x][y + yy]);
    }
}

// ---------------------------------------------------------------------------
// monotone float<->uint encoding for atomicMax on floats
// ---------------------------------------------------------------------------
__device__ __forceinline__ unsigned enc_f(float f) {
    unsigned u = __float_as_uint(f);
    return (u >> 31) ? ~u : (u | 0x80000000u);
}
__device__ __forceinline__ float dec_f(unsigned e) {
    return (e >> 31) ? __uint_as_float(e ^ 0x80000000u) : __uint_as_float(~e);
}

// ---------------------------------------------------------------------------
// Fully fused GAT stage, MFMA aggregation.
// One block (256 thr) per (graph, head). h bf16 [N][H*128].
// O[d][c] = sum_s At[s][d]*h[s][c] via mfma_16x16x32_bf16:
//   A = At^T as bf16 hi/lo pair (f32-equivalent alpha precision)
//   B = h^T in chunk-XOR-swizzled LDS
// POOL=1: fused per-graph column max only.
// ---------------------------------------------------------------------------
// swizzled byte addr of chunk (s>>3) in row `row` of a [rows][32 bf16] region
__device__ __forceinline__ unsigned swz32(int row, int chunk) {
    return (unsigned)((row << 6) + ((chunk ^ (row & 3)) << 4));
}

template <int POOL>
__global__ __launch_bounds__(256) void gat_fused_kernel(
    const ushort_t* __restrict__ h, const int* __restrict__ esrc,
    const int* __restrict__ edst, const float* __restrict__ a_src,
    const float* __restrict__ a_dst, const float* __restrict__ bias,
    ushort_t* __restrict__ out, int H)
{
    const int g    = blockIdx.x / H;
    const int hd   = blockIdx.x % H;
    const int tid  = threadIdx.x;
    const int lane = tid & 63;
    const int wave = tid >> 6;
    const int base = g * NPG;
    const int HC   = H * CCH;

    // uni: phase A = h_row bf16 [32][128]; phase B = AtH[1024]+AtL[1024] bf16
    __shared__ __align__(16) char uni[NPG * CCH * 2];          // 8 KB
    __shared__ __align__(16) ushort_t hT[CCH * 32];            // 8 KB swizzled [c][s]
    __shared__ float At[NPG][NPG];                             // 4 KB, At[s][d]
    __shared__ float asv[CCH], adv[CCH];
    __shared__ float as_l[NPG], ad_l[NPG];
    __shared__ unsigned m_l[NPG];
    __shared__ float den_l[NPG];
    __shared__ float sc_l[EPG + NPG];
    __shared__ unsigned char s_l[EPG + NPG], d_l[EPG + NPG];

    ushort_t (*h_row)[CCH] = (ushort_t(*)[CCH])uni;
    ushort_t* AtH = (ushort_t*)uni;            // overlays h_row after its death
    ushort_t* AtL = (ushort_t*)(uni + 2048);

    // ---- hoist edge-index loads (hide HBM latency under staging) ----
    int es_r = 0, ed_r = 0;
    if (tid < EPG) {
        es_r = esrc[g * EPG + tid] - base;
        ed_r = edst[g * EPG + tid] - base;
    } else if (tid < EPG + NPG) {
        es_r = ed_r = tid - EPG;               // self-loop
    }

    // ---- stage h slice raw bf16, zero At, load a-vectors ----
    {
        const int r4 = tid >> 6;               // 0..3
        const int cp = (tid & 63) * 2;         // col pair
        #pragma unroll
        for (int rr = 0; rr < NPG; rr += 4) {
            const int r = rr + r4;
            unsigned v = *(const unsigned*)(h + (size_t)(base + r) * HC + hd * CCH + cp);
            *(unsigned*)&h_row[r][cp] = v;
        }
    }
    #pragma unroll
    for (int i = tid; i < NPG * NPG; i += 256) ((float*)At)[i] = 0.0f;
    if (tid < CCH) asv[tid] = a_src[hd * CCH + tid];
    else           adv[tid - CCH] = a_dst[hd * CCH + tid - CCH];
    if (tid < NPG) { m_l[tid] = 0u; den_l[tid] = 0.0f; }
    __syncthreads();

    // ---- attention logits (wave-parallel shuffle reduce) ----
    for (int n = wave; n < NPG; n += 4) {
        float v0 = b2f(h_row[n][lane]), v1 = b2f(h_row[n][lane + 64]);
        float s = v0 * asv[lane] + v1 * asv[lane + 64];
        float d = v0 * adv[lane] + v1 * adv[lane + 64];
        #pragma unroll
        for (int o = 32; o > 0; o >>= 1) {
            s += __shfl_xor(s, o, 64);
            d += __shfl_xor(d, o, 64);
        }
        if (lane == 0) { as_l[n] = s; ad_l[n] = d; }
    }
    // ---- transpose h_row -> hT (swizzled); thread owns col c, rows s0..s0+15
    {
        const int c  = tid & 127;
        const int s0 = (tid >> 7) * 16;        // 0 or 16
        #pragma unroll
        for (int hh = 0; hh < 2; ++hh) {
            const int sb = s0 + hh * 8;
            unsigned pk[4];
            #pragma unroll
            for (int p = 0; p < 4; ++p) {
                unsigned lo = h_row[sb + 2 * p][c];
                unsigned hi = h_row[sb + 2 * p + 1][c];
                pk[p] = lo | (hi << 16);
            }
            *(uint4*)((char*)hT + swz32(c, sb >> 3)) = make_uint4(pk[0], pk[1], pk[2], pk[3]);
        }
    }
    __syncthreads();

    // ---- edge scores + segment max ----
    if (tid < EPG + NPG) {
        float e = as_l[es_r] + ad_l[ed_r];
        e = (e >= 0.0f) ? e : 0.2f * e;        // leaky_relu 0.2
        sc_l[tid] = e;
        s_l[tid] = (unsigned char)es_r;
        d_l[tid] = (unsigned char)ed_r;
        atomicMax(&m_l[ed_r], enc_f(e));
    }
    __syncthreads();

    // ---- exp + segment sum ----
    if (tid < EPG + NPG) {
        float ex = expf(sc_l[tid] - dec_f(m_l[d_l[tid]]));
        sc_l[tid] = ex;
        atomicAdd(&den_l[d_l[tid]], ex);
    }
    __syncthreads();

    // ---- scatter alpha into dense At[s][d] ----
    if (tid < EPG + NPG) {
        float al = sc_l[tid] / (den_l[d_l[tid]] + 1e-16f);
        atomicAdd(&At[s_l[tid]][d_l[tid]], al);
    }
    __syncthreads();

    // ---- At[s][d] -> At^T hi/lo bf16 rows (h_row dead; AtH/AtL overlay) ---
    {
        const int d  = tid >> 3;               // 0..31
        const int s4 = (tid & 7) * 4;          // 0,4,..,28
        float v0 = At[s4 + 0][d], v1 = At[s4 + 1][d];
        float v2 = At[s4 + 2][d], v3 = At[s4 + 3][d];
        ushort_t h0 = f2b(v0), h1 = f2b(v1), h2 = f2b(v2), h3 = f2b(v3);
        ushort_t l0 = f2b(v0 - b2f(h0)), l1 = f2b(v1 - b2f(h1));
        ushort_t l2 = f2b(v2 - b2f(h2)), l3 = f2b(v3 - b2f(h3));
        const unsigned a = swz32(d, s4 >> 3) + (unsigned)((s4 & 7) * 2);
        *(uint2*)((char*)AtH + a) = make_uint2((unsigned)h0 | ((unsigned)h1 << 16),
                                               (unsigned)h2 | ((unsigned)h3 << 16));
        *(uint2*)((char*)AtL + a) = make_uint2((unsigned)l0 | ((unsigned)l1 << 16),
                                               (unsigned)l2 | ((unsigned)l3 << 16));
    }
    __syncthreads();

    // ---- MFMA aggregation: per wave 1 d-block x 4 c-tiles, hi+lo ----
    const int fr = lane & 15, fq = lane >> 4;
    const int dblk  = wave & 1;
    const int cbase = (wave >> 1) * 64;

    bf16x8_t aH = *(const bf16x8_t*)((char*)AtH + swz32(dblk * 16 + fr, fq));
    bf16x8_t aL = *(const bf16x8_t*)((char*)AtL + swz32(dblk * 16 + fr, fq));
    bf16x8_t bfr[4];
    #pragma unroll
    for (int q = 0; q < 4; ++q)
        bfr[q] = *(const bf16x8_t*)((char*)hT + swz32(cbase + q * 16 + fr, fq));

    f32x4_t acc[4] = {};
    #pragma unroll
    for (int q = 0; q < 4; ++q) {
        acc[q] = __builtin_amdgcn_mfma_f32_16x16x32_bf16(aH, bfr[q], acc[q], 0, 0, 0);
        acc[q] = __builtin_amdgcn_mfma_f32_16x16x32_bf16(aL, bfr[q], acc[q], 0, 0, 0);
    }

    if (POOL) {
        float* pool2 = (float*)At;             // At dead; needs 256 floats
        #pragma unroll
        for (int q = 0; q < 4; ++q) {
            const int c = cbase + q * 16 + fr;
            const float bb = bias[hd * CCH + c];
            float m = -INFINITY;
            #pragma unroll
            for (int r = 0; r < 4; ++r) {
                float v = acc[q][r] + bb;
                v = (v > 0.0f) ? v : (expf(v) - 1.0f);
                m = fmaxf(m, v);
            }
            m = fmaxf(m, __shfl_xor(m, 16, 64));
            m = fmaxf(m, __shfl_xor(m, 32, 64));
            if (fq == 0) pool2[dblk * CCH + c] = m;
        }
        __syncthreads();
        if (tid < CCH)
            out[(size_t)g * CCH + tid] = f2b(fmaxf(pool2[tid], pool2[CCH + tid]));
    } else {
        #pragma unroll
        for (int q = 0; q < 4; ++q) {
            const int c = cbase + q * 16 + fr;
            const float bb = bias[hd * CCH + c];
            #pragma unroll
            for (int r = 0; r < 4; ++r) {
                const int d = dblk * 16 + fq * 4 + r;
                float v = acc[q][r] + bb;
                v = (v > 0.0f) ? v : (expf(v) - 1.0f);
                out[(size_t)(base + d) * HC + hd * CCH + c] = f2b(v);
            }
        }
    }
}

// ---------------------------------------------------------------------------
// Per-row inverse L2 norm (gene branch, fp32 input)
// ---------------------------------------------------------------------------
__global__ __launch_bounds__(256) void rownorm_kernel(
    const float* __restrict__ x, float* __restrict__ inv, int K)
{
    const int row = blockIdx.x;
    const int tid = threadIdx.x;
    const float* xp = x + (size_t)row * K;
    float s = 0.f;
    for (int k = tid; k < K; k += 256) { float v = xp[k]; s += v * v; }
    __shared__ float red[256];
    red[tid] = s;
    __syncthreads();
    for (int o = 128; o > 0; o >>= 1) {
        if (tid < o) red[tid] += red[tid + o];
        __syncthreads();
    }
    if (tid == 0) inv[row] = 1.0f / fmaxf(sqrtf(red[0]), 1e-12f);
}

// ---------------------------------------------------------------------------
// Column-block copy helpers (into concat buffers)
// ---------------------------------------------------------------------------
__global__ __launch_bounds__(256) void copyb_kernel(
    ushort_t* __restrict__ dst, int ld, int off,
    const ushort_t* __restrict__ src, int rows, int cols)
{
    int idx = blockIdx.x * 256 + threadIdx.x;
    if (idx >= rows * cols) return;
    int r = idx / cols, c = idx - r * cols;
    dst[(size_t)r * ld + off + c] = src[idx];
}

__global__ __launch_bounds__(256) void castcols_kernel(
    ushort_t* __restrict__ dst, int ld, int off,
    const float* __restrict__ src, int rows, int cols)
{
    int idx = blockIdx.x * 256 + threadIdx.x;
    if (idx >= rows * cols) return;
    int r = idx / cols, c = idx - r * cols;
    dst[(size_t)r * ld + off + c] = f2b(src[idx]);
}

// ---------------------------------------------------------------------------
// Final N_TASKS=1: out[b] = y[b,:256] . w + bout   (y bf16)
// ---------------------------------------------------------------------------
__global__ __launch_bounds__(256) void final_kernel(
    const ushort_t* __restrict__ y, const float* __restrict__ w,
    const float* __restrict__ b, float* __restrict__ out)
{
    const int row = blockIdx.x;
    const int tid = threadIdx.x;
    float v = b2f(y[(size_t)row * 256 + tid]) * w[tid];
    __shared__ float red[256];
    red[tid] = v;
    __syncthreads();
    for (int o = 128; o > 0; o >>= 1) {
        if (tid < o) red[tid] += red[tid + o];
        __syncthreads();
    }
    if (tid == 0) out[row] = red[0] + b[0];
}

// ---------------------------------------------------------------------------
// Host side
// ---------------------------------------------------------------------------
static inline void launch_gemm(const ushort_t* A, const ushort_t* BT,
                               const float* bias, ushort_t* C,
                               int M, int N, int K, int act, hipStream_t stream)
{
    dim3 grid(N / GBN, M / GBM);
    gemm_bf16_kernel<<<grid, 256, 0, stream>>>(A, BT, bias, C, M, N, K, act);
}

// split-K GEMM: partials into `part` (fp32), then reduce with bias+act
static inline void launch_gemm_sk(const ushort_t* A, const ushort_t* BT,
                                  const float* bias, ushort_t* C, float* part,
                                  int M, int N, int K, int S, int act,
                                  hipStream_t stream)
{
    if (S <= 1) { launch_gemm(A, BT, bias, C, M, N, K, act, stream); return; }
    const int iters = K / GBK;
    const int ipc   = (iters + S - 1) / S;         // iters per chunk
    const int S_eff = (iters + ipc - 1) / ipc;     // no empty chunks
    const int KC    = ipc * GBK;
    dim3 grid(N / GBN, M / GBM, S_eff);
    gemm_bf16_part_kernel<<<grid, 256, 0, stream>>>(A, BT, part, M, N, K, KC);
    const int MN = M * N;
    reduce_kernel<<<(MN / 4 + 255) / 256, 256, 0, stream>>>(
        part, bias, C, MN, N, S_eff, act);
}

// 8-phase 256^2 split-K GEMM path (M%256==0, N%256==0, K%128==0)
static inline void launch_gemm_8ph(const ushort_t* A, const ushort_t* BT,
                                   const float* bias, ushort_t* C, float* part,
                                   int M, int N, int K, int S, int act,
                                   hipStream_t stream)
{
    const int iters = K >> 7;                      // 128-K iterations
    const int ipc   = (iters + S - 1) / S;
    const int S_eff = (iters + ipc - 1) / ipc;
    const int gx = N >> 8, gy = M >> 8;
    const int nwg = gx * gy * S_eff;
    static bool attr_done = false;
    if (!attr_done) {
        (void)hipFuncSetAttribute((const void*)gemm_bf16_8ph_kernel,
                                  hipFuncAttributeMaxDynamicSharedMemorySize, 131072);
        attr_done = true;
    }
    gemm_bf16_8ph_kernel<<<dim3(nwg), 512, 131072, stream>>>(A, BT, part, M, N, K, ipc);
    const int MN = M * N;
    reduce_kernel<<<(MN / 4 + 255) / 256, 256, 0, stream>>>(
        part, bias, C, MN, N, S_eff, act);
}

static inline void launch_castT(const float* W, ushort_t* WT, int K, int N,
                                int Kpad, hipStream_t stream)
{
    dim3 grid((N + 31) / 32, (Kpad + 31) / 32);
    castT_kernel<<<grid, 256, 0, stream>>>(W, WT, K, N, Kpad);
}

extern "C" void kernel_launch(void* const* d_in, const int* in_sizes, int n_in,
                              void* d_out, int out_size, void* d_ws, size_t ws_size,
                              hipStream_t stream)
{
    const float* x1      = (const float*)d_in[0];
    const float* x2      = (const float*)d_in[1];
    const float* gene    = (const float*)d_in[2];
    const float* drr     = (const float*)d_in[3];
    const float* drc     = (const float*)d_in[4];
    const float* prot    = (const float*)d_in[5];
    const int*   ei1     = (const int*)d_in[6];
    const int*   ei2     = (const int*)d_in[7];
    const float* W_gat1  = (const float*)d_in[9];
    const float* b_gat1  = (const float*)d_in[10];
    const float* a_src1  = (const float*)d_in[11];
    const float* a_dst1  = (const float*)d_in[12];
    const float* W_gat2  = (const float*)d_in[13];
    const float* b_gat2  = (const float*)d_in[14];
    const float* a_src2  = (const float*)d_in[15];
    const float* a_dst2  = (const float*)d_in[16];
    const float* W_fcg   = (const float*)d_in[17];
    const float* b_fcg   = (const float*)d_in[18];
    const float* Wr1     = (const float*)d_in[19];
    const float* br1     = (const float*)d_in[20];
    const float* Wr2     = (const float*)d_in[21];
    const float* br2     = (const float*)d_in[22];
    const float* Wr3     = (const float*)d_in[23];
    const float* br3     = (const float*)d_in[24];
    const float* Wp1     = (const float*)d_in[25];
    const float* bp1     = (const float*)d_in[26];
    const float* Wp2     = (const float*)d_in[27];
    const float* bp2     = (const float*)d_in[28];
    const float* Wp3     = (const float*)d_in[29];
    const float* bp3     = (const float*)d_in[30];
    const float* Wdrr    = (const float*)d_in[31];
    const float* bdrr    = (const float*)d_in[32];
    const float* Wdrc    = (const float*)d_in[33];
    const float* bdrc    = (const float*)d_in[34];
    const float* Wf1     = (const float*)d_in[35];
    const float* bf1     = (const float*)d_in[36];
    const float* Wf2     = (const float*)d_in[37];
    const float* bf2     = (const float*)d_in[38];
    const float* Wout    = (const float*)d_in[39];
    const float* bout    = (const float*)d_in[40];
    float* outp = (float*)d_out;

    char* ws = (char*)d_ws;
    size_t off = 0;
    auto alloc = [&](size_t bytes) -> char* {
        char* r = ws + off;
        off += (bytes + 255) & ~(size_t)255;
        return r;
    };

    char* BIG0 = alloc(134217728);
    char* BIG1 = alloc(67108864);

    ushort_t* go1f   = (ushort_t*)BIG0;
    ushort_t* h1     = (ushort_t*)BIG1;
    float*    part   = (float*)BIG1;
    ushort_t* WT_r1  = (ushort_t*)(BIG0 + 0);           // 2048x18048 = 73,924,608
    ushort_t* gene_nb= (ushort_t*)(BIG0 + 73924608);    // 1024x18048 = 36,962,304
    ushort_t* cell1  = (ushort_t*)(BIG0 + 110886912);   // 1024x2048  =  4,194,304
    ushort_t* WT_r2  = (ushort_t*)(BIG0 + 115081216);   // 512x2048   =  2,097,152
    ushort_t* WT_p2  = (ushort_t*)(BIG0 + 117178368);   // 512x1024   =  1,048,576
    ushort_t* WT_p1  = (ushort_t*)(BIG0 + 118226944);   // 1024x6784  = 13,895,680

    ushort_t* xb     = (ushort_t*)alloc((size_t)NNODES * 96 * 2);        // per-drug
    char*     h2reg  = alloc((size_t)2 * NNODES * 128 * 2);              // 16.8 MB
    char*     catreg = alloc((size_t)2 * 1024 * 2176 * 2);               //  8.9 MB
    ushort_t* h2f    = (ushort_t*)h2reg;     // drug phase
    ushort_t* protb  = (ushort_t*)h2reg;     // MLP phase alias (13.9 MB <= 16.8)
    ushort_t* cat1   = (ushort_t*)catreg;
    ushort_t* cat2   = (ushort_t*)(catreg + (size_t)1024 * 2176 * 2);
    ushort_t* pooled = (ushort_t*)alloc((size_t)2 * BATCH * 128 * 2);
    ushort_t* gpair  = (ushort_t*)alloc((size_t)2 * BATCH * 128 * 2);
    float*    invn   = (float*)alloc((size_t)BATCH * 4);
    ushort_t* cvec   = (ushort_t*)alloc((size_t)BATCH * 256 * 2);
    ushort_t* pvec   = (ushort_t*)alloc((size_t)BATCH * 256 * 2);
    ushort_t* y1     = (ushort_t*)alloc((size_t)BATCH * 512 * 2);
    ushort_t* y2     = (ushort_t*)alloc((size_t)BATCH * 256 * 2);
    ushort_t* WT_g1  = (ushort_t*)alloc((size_t)1024 * 96 * 2);
    ushort_t* WT_g2  = (ushort_t*)alloc((size_t)128 * 1024 * 2);
    ushort_t* WT_fcg = (ushort_t*)alloc((size_t)128 * 128 * 2);
    ushort_t* WT_r3  = (ushort_t*)alloc((size_t)256 * 512 * 2);
    ushort_t* WT_p3  = (ushort_t*)alloc((size_t)256 * 512 * 2);
    ushort_t* WT_f2  = (ushort_t*)alloc((size_t)256 * 512 * 2);
    ushort_t* WT_drr = (ushort_t*)alloc((size_t)2176 * 2176 * 2);
    ushort_t* WT_drc = (ushort_t*)alloc((size_t)2176 * 2176 * 2);
    ushort_t* WT_f1  = (ushort_t*)alloc((size_t)512 * 4864 * 2);
    ushort_t* p1b    = (ushort_t*)alloc((size_t)1024 * 1024 * 2);
    ushort_t* p2b    = (ushort_t*)alloc((size_t)1024 * 512 * 2);
    ushort_t* cell2  = (ushort_t*)alloc((size_t)1024 * 512 * 2);
    ushort_t* d1     = (ushort_t*)alloc((size_t)1024 * 2176 * 2);
    ushort_t* d2     = (ushort_t*)alloc((size_t)1024 * 2176 * 2);
    ushort_t* ybuf   = (ushort_t*)alloc((size_t)1024 * 4864 * 2);

    const int E = in_sizes[6] / 2;   // 131072

    // ---------------- drug-phase weight casts ----------------
    launch_castT(W_gat1, WT_g1, INFEAT, 1024, 96, stream);
    launch_castT(W_gat2, WT_g2, 1024, 128, 1024, stream);
    launch_castT(W_fcg,  WT_fcg, 128, 128, 128, stream);

    // ---------------- drug branch: GAT1 per drug, write into shared go1f ---
    for (int drug = 0; drug < 2; drug++) {
        const float* x  = drug ? x2 : x1;
        const int*   es = (drug ? ei2 : ei1);
        const int*   ed = es + E;
        ushort_t* go1d = go1f + (size_t)drug * NNODES * 1024;

        cast_rows_kernel<<<(NNODES * 96 + 255) / 256, 256, 0, stream>>>(
            x, nullptr, xb, NNODES, INFEAT, 96);
        launch_gemm(xb, WT_g1, nullptr, h1, NNODES, 1024, 96, ACT_NONE, stream);
        gat_fused_kernel<0><<<BATCH * NHEAD, 256, 0, stream>>>(
            h1, es, ed, a_src1, a_dst1, b_gat1, go1d, NHEAD);
    }

    // ---------------- batched GAT2 GEMM (M=65536 -> 512 blocks) ------------
    launch_gemm(go1f, WT_g2, nullptr, h2f, 2 * NNODES, 128, 1024, ACT_NONE, stream);

    // BIG0 (go1f) now dead -> cast MLP-phase weights into it
    launch_castT(Wr1, WT_r1, GENE, 2048, GENEP, stream);
    launch_castT(Wr2, WT_r2, 2048, 512, 2048, stream);
    launch_castT(Wp1, WT_p1, PROT, 1024, PROTP, stream);
    launch_castT(Wp2, WT_p2, 1024, 512, 1024, stream);
    launch_castT(Wr3, WT_r3, 512, 256, 512, stream);
    launch_castT(Wp3, WT_p3, 512, 256, 512, stream);
    launch_castT(Wf2, WT_f2, 512, 256, 512, stream);
    launch_castT(Wdrr, WT_drr, 2176, 2176, 2176, stream);
    launch_castT(Wdrc, WT_drc, 2176, 2176, 2176, stream);
    launch_castT(Wf1, WT_f1, 4864, 512, 4864, stream);

    // ---------------- GAT2 fused (attn + softmax + agg + maxpool) ----------
    for (int drug = 0; drug < 2; drug++) {
        const int* es = (drug ? ei2 : ei1);
        const int* ed = es + E;
        gat_fused_kernel<1><<<BATCH, 256, 0, stream>>>(
            h2f + (size_t)drug * NNODES * 128, es, ed,
            a_src2, a_dst2, b_gat2, pooled + (size_t)drug * BATCH * 128, 1);
    }
    launch_gemm(pooled, WT_fcg, b_fcg, gpair, 2 * BATCH, 128, 128, ACT_RELU, stream);

    // ---------------- gene branch (8-phase split-K for the big-K GEMM) -----
    rownorm_kernel<<<BATCH, 256, 0, stream>>>(gene, invn, GENE);
    cast_rows_kernel<<<(BATCH * GENEP + 255) / 256, 256, 0, stream>>>(
        gene, invn, gene_nb, BATCH, GENE, GENEP);
    launch_gemm_8ph(gene_nb, WT_r1, br1, cell1, part, BATCH, 2048, GENEP, 8, ACT_RELU, stream);
    launch_gemm_sk(cell1, WT_r2, br2, cell2, part, BATCH, 512, 2048, 8, ACT_RELU, stream);
    launch_gemm_sk(cell2, WT_r3, br3, cvec, part, BATCH, 256, 512, 4, ACT_RELU, stream);

    // ---------------- protein branch (8-phase for K=6784; protb aliases h2f)
    cast_rows_kernel<<<(BATCH * PROTP + 255) / 256, 256, 0, stream>>>(
        prot, nullptr, protb, BATCH, PROT, PROTP);
    launch_gemm_8ph(protb, WT_p1, bp1, p1b, part, BATCH, 1024, PROTP, 16, ACT_ELU, stream);
    launch_gemm_sk(p1b, WT_p2, bp2, p2b, part, BATCH, 512, 1024, 4, ACT_ELU, stream);
    launch_gemm_sk(p2b, WT_p3, bp3, pvec, part, BATCH, 256, 512, 4, ACT_RELU, stream);

    // ---------------- fingerprint fusion ----------------
    {
        int n = BATCH * CCH;
        copyb_kernel<<<(n + 255) / 256, 256, 0, stream>>>(cat1, 2176, 0, gpair, BATCH, CCH);
        copyb_kernel<<<(n + 255) / 256, 256, 0, stream>>>(cat2, 2176, 0, gpair + BATCH * CCH, BATCH, CCH);
        n = BATCH * FPD;
        castcols_kernel<<<(n + 255) / 256, 256, 0, stream>>>(cat1, 2176, CCH, drr, BATCH, FPD);
        castcols_kernel<<<(n + 255) / 256, 256, 0, stream>>>(cat2, 2176, CCH, drc, BATCH, FPD);
    }
    launch_gemm_sk(cat1, WT_drr, bdrr, d1, part, BATCH, 2176, 2176, 4, ACT_RELU, stream);
    launch_gemm_sk(cat2, WT_drc, bdrc, d2, part, BATCH, 2176, 2176, 4, ACT_RELU, stream);

    // ---------------- concat + predictor ----------------
    {
        int n = BATCH * 2176;
        copyb_kernel<<<(n + 255) / 256, 256, 0, stream>>>(ybuf, 4864, 0,    d1, BATCH, 2176);
        copyb_kernel<<<(n + 255) / 256, 256, 0, stream>>>(ybuf, 4864, 2176, d2, BATCH, 2176);
        n = BATCH * 256;
        copyb_kernel<<<(n + 255) / 256, 256, 0, stream>>>(ybuf, 4864, 4352, cvec, BATCH, 256);
        copyb_kernel<<<(n + 255) / 256, 256, 0, stream>>>(ybuf, 4864, 4608, pvec, BATCH, 256);
    }
    launch_gemm_sk(ybuf, WT_f1, bf1, y1, part, BATCH, 512, 4864, 8, ACT_RELU, stream);
    launch_gemm_sk(y1, WT_f2, bf2, y2, part, BATCH, 256, 512, 4, ACT_RELU, stream);
    final_kernel<<<BATCH, 256, 0, stream>>>(y2, Wout, bout, outp);
}

// Round 3
// 1081.919 us; speedup vs baseline: 1.1612x; 1.0484x over previous
//
#include <hip/hip_runtime.h>
#include <math.h>

// ---------------------------------------------------------------------------
// Model dims (fixed by the reference)
// ---------------------------------------------------------------------------
#define BATCH   1024
#define NPG     32
#define NNODES  (BATCH * NPG)      // 32768 per drug
#define EPG     128
#define INFEAT  78
#define CCH     128
#define NHEAD   8
#define GENE    18000
#define GENEP   18048              // padded to %128 (8-phase kernel needs K%128)
#define PROT    6688
#define PROTP   6784               // padded to %128
#define FPD     2048

#define ACT_NONE 0
#define ACT_RELU 1
#define ACT_ELU  2

typedef unsigned short ushort_t;
typedef __bf16 bf16x8_t __attribute__((ext_vector_type(8)));
typedef float  f32x4_t  __attribute__((ext_vector_type(4)));

__device__ __forceinline__ float b2f(ushort_t u) {
    return __uint_as_float(((unsigned)u) << 16);
}
__device__ __forceinline__ ushort_t f2b(float f) {
    unsigned x = __float_as_uint(f);
    return (ushort_t)((x + 0x7fffu + ((x >> 16) & 1u)) >> 16);   // RNE
}

// ---------------------------------------------------------------------------
// bf16 MFMA GEMM (m97 structure): C[M,N] = act(A[M,K] @ BT[N,K]^T + bias)
// A, BT bf16 (K%32==0); C bf16; bias fp32. M%128==0, N%128==0.
// 128x128 tile, BK=32, 256 threads (2x2 waves of 64x64), global_load_lds.
// ---------------------------------------------------------------------------
#define GBM 128
#define GBN 128
#define GBK 32

__device__ __forceinline__ void gemm_core(
    const ushort_t* __restrict__ A, const ushort_t* __restrict__ BT,
    int K, int kb, int ke, int row0, int col0,
    ushort_t* Asl, ushort_t* Bsl, f32x4_t acc[4][4])
{
    const int tid  = threadIdx.x;
    const int wave = tid >> 6;
    const int lane = tid & 63;
    const int wr   = wave >> 1;
    const int wc   = wave & 1;
    const int srow = lane >> 2;        // 0..15
    const int skel = (lane & 3) * 8;   // bf16 elem offset

    for (int k0 = kb; k0 < ke; k0 += GBK) {
        __syncthreads();               // protect LDS from previous iteration
        #pragma unroll
        for (int t = 0; t < 2; ++t) {
            const int rg = wave * 32 + t * 16;                   // wave-uniform
            const ushort_t* ga = A + (size_t)(row0 + rg + srow) * K + k0 + skel;
            __builtin_amdgcn_global_load_lds(
                (const __attribute__((address_space(1))) void*)ga,
                (__attribute__((address_space(3))) void*)&Asl[rg * GBK], 16, 0, 0);
            const ushort_t* gb = BT + (size_t)(col0 + rg + srow) * K + k0 + skel;
            __builtin_amdgcn_global_load_lds(
                (const __attribute__((address_space(1))) void*)gb,
                (__attribute__((address_space(3))) void*)&Bsl[rg * GBK], 16, 0, 0);
        }
        __syncthreads();

        const int fr = lane & 15;
        const int fq = lane >> 4;
        bf16x8_t av[4], bv[4];
        #pragma unroll
        for (int i = 0; i < 4; ++i)
            av[i] = *(const bf16x8_t*)&Asl[(wr * 64 + i * 16 + fr) * GBK + fq * 8];
        #pragma unroll
        for (int j = 0; j < 4; ++j)
            bv[j] = *(const bf16x8_t*)&Bsl[(wc * 64 + j * 16 + fr) * GBK + fq * 8];
        #pragma unroll
        for (int i = 0; i < 4; ++i)
            #pragma unroll
            for (int j = 0; j < 4; ++j)
                acc[i][j] = __builtin_amdgcn_mfma_f32_16x16x32_bf16(
                    av[i], bv[j], acc[i][j], 0, 0, 0);
    }
}

__global__ __launch_bounds__(256) void gemm_bf16_kernel(
    const ushort_t* __restrict__ A, const ushort_t* __restrict__ BT,
    const float* __restrict__ bias, ushort_t* __restrict__ C,
    int M, int N, int K, int act)
{
    __shared__ ushort_t Asl[GBM * GBK];
    __shared__ ushort_t Bsl[GBN * GBK];
    const int lane = threadIdx.x & 63;
    const int wave = threadIdx.x >> 6;
    const int wr = wave >> 1, wc = wave & 1;
    const int row0 = blockIdx.y * GBM;
    const int col0 = blockIdx.x * GBN;

    f32x4_t acc[4][4] = {};
    gemm_core(A, BT, K, 0, K, row0, col0, Asl, Bsl, acc);

    const int fr = lane & 15;
    const int fq = lane >> 4;
    #pragma unroll
    for (int i = 0; i < 4; ++i) {
        #pragma unroll
        for (int j = 0; j < 4; ++j) {
            const int gn = col0 + wc * 64 + j * 16 + fr;
            const float bb = bias ? bias[gn] : 0.0f;
            #pragma unroll
            for (int r = 0; r < 4; ++r) {
                const int gm = row0 + wr * 64 + i * 16 + fq * 4 + r;
                float v = acc[i][j][r] + bb;
                if (act == ACT_RELU)     v = fmaxf(v, 0.0f);
                else if (act == ACT_ELU) v = (v > 0.0f) ? v : (expf(v) - 1.0f);
                C[(size_t)gm * N + gn] = f2b(v);
            }
        }
    }
}

// split-K variant: grid.z = chunk index, fp32 partials out (no bias/act)
__global__ __launch_bounds__(256) void gemm_bf16_part_kernel(
    const ushort_t* __restrict__ A, const ushort_t* __restrict__ BT,
    float* __restrict__ part, int M, int N, int K, int KC)
{
    __shared__ ushort_t Asl[GBM * GBK];
    __shared__ ushort_t Bsl[GBN * GBK];
    const int lane = threadIdx.x & 63;
    const int wave = threadIdx.x >> 6;
    const int wr = wave >> 1, wc = wave & 1;
    const int row0 = blockIdx.y * GBM;
    const int col0 = blockIdx.x * GBN;
    const int z    = blockIdx.z;
    const int kb   = z * KC;
    const int ke   = min(K, kb + KC);

    f32x4_t acc[4][4] = {};
    gemm_core(A, BT, K, kb, ke, row0, col0, Asl, Bsl, acc);

    const int fr = lane & 15;
    const int fq = lane >> 4;
    float* po = part + (size_t)z * M * N;
    #pragma unroll
    for (int i = 0; i < 4; ++i)
        #pragma unroll
        for (int j = 0; j < 4; ++j) {
            const int gn = col0 + wc * 64 + j * 16 + fr;
            #pragma unroll
            for (int r = 0; r < 4; ++r) {
                const int gm = row0 + wr * 64 + i * 16 + fq * 4 + r;
                po[(size_t)gm * N + gn] = acc[i][j][r];
            }
        }
}

// sum S partials + bias + act -> bf16 written at C[r*Cld + Coff + n], n < Nb
__global__ __launch_bounds__(256) void reduce_kernel(
    const float* __restrict__ part, const float* __restrict__ bias,
    ushort_t* __restrict__ C, int MN, int N, int S, int act,
    int Nb, int Cld, int Coff)
{
    int i4 = (blockIdx.x * 256 + threadIdx.x) * 4;
    if (i4 >= MN) return;
    const int r = i4 / N, n = i4 - r * N;
    if (n >= Nb) return;                    // zero-padded cols: no store
    float4 s = *(const float4*)&part[i4];
    for (int z = 1; z < S; ++z) {
        float4 v = *(const float4*)&part[(size_t)z * MN + i4];
        s.x += v.x; s.y += v.y; s.z += v.z; s.w += v.w;
    }
    float o[4] = { s.x, s.y, s.z, s.w };
    if (bias) { o[0] += bias[n]; o[1] += bias[n+1]; o[2] += bias[n+2]; o[3] += bias[n+3]; }
    ushort_t rr[4];
    #pragma unroll
    for (int k = 0; k < 4; ++k) {
        float v = o[k];
        if (act == ACT_RELU)     v = fmaxf(v, 0.0f);
        else if (act == ACT_ELU) v = (v > 0.0f) ? v : (expf(v) - 1.0f);
        rr[k] = f2b(v);
    }
    unsigned pk0 = (unsigned)rr[0] | ((unsigned)rr[1] << 16);
    unsigned pk1 = (unsigned)rr[2] | ((unsigned)rr[3] << 16);
    *(uint2*)&C[(size_t)r * Cld + Coff + n] = make_uint2(pk0, pk1);
}

// ---------------------------------------------------------------------------
// 8-phase 256x256 split-K GEMM (T1+T2+T3+T4+T5), for big-K skinny GEMMs.
// part[z][M][N] fp32 = A[M,K] @ BT[N,K]^T over K-chunk z.
// Requirements: M%256==0, N%256==0, K%128==0.
// ---------------------------------------------------------------------------
#define DSREAD(dst, addr) asm volatile("ds_read_b128 %0, %1" : "=v"(dst) : "v"(addr))

template <int MH>
__device__ __forceinline__ void read_A8(bf16x8_t (&av)[4][2], unsigned b0, unsigned b1)
{
    DSREAD(av[0][0], b0 + (MH * 4 + 0) * 2048);
    DSREAD(av[0][1], b1 + (MH * 4 + 0) * 2048);
    DSREAD(av[1][0], b0 + (MH * 4 + 1) * 2048);
    DSREAD(av[1][1], b1 + (MH * 4 + 1) * 2048);
    DSREAD(av[2][0], b0 + (MH * 4 + 2) * 2048);
    DSREAD(av[2][1], b1 + (MH * 4 + 2) * 2048);
    DSREAD(av[3][0], b0 + (MH * 4 + 3) * 2048);
    DSREAD(av[3][1], b1 + (MH * 4 + 3) * 2048);
}

template <int NH>
__device__ __forceinline__ void read_B8(bf16x8_t (&bvh)[2][2], unsigned b0, unsigned b1)
{
    DSREAD(bvh[0][0], b0 + (NH * 2 + 0) * 2048);
    DSREAD(bvh[0][1], b1 + (NH * 2 + 0) * 2048);
    DSREAD(bvh[1][0], b0 + (NH * 2 + 1) * 2048);
    DSREAD(bvh[1][1], b1 + (NH * 2 + 1) * 2048);
}

template <int MH, int NH>
__device__ __forceinline__ void mfma_quad(const bf16x8_t (&av)[4][2],
                                          const bf16x8_t (&bvh)[2][2],
                                          f32x4_t (&acc)[8][4])
{
    #pragma unroll
    for (int qq = 0; qq < 4; ++qq)
        #pragma unroll
        for (int pp = 0; pp < 2; ++pp)
            #pragma unroll
            for (int ss = 0; ss < 2; ++ss)
                acc[MH * 4 + qq][NH * 2 + pp] = __builtin_amdgcn_mfma_f32_16x16x32_bf16(
                    av[qq][ss], bvh[pp][ss], acc[MH * 4 + qq][NH * 2 + pp], 0, 0, 0);
}

// stage one 128-row x 64-col half-tile (2 x global_load_lds of 16B per thread)
__device__ __forceinline__ void stage_half8(
    const ushort_t* __restrict__ G, int rc0, int K, int kt,
    unsigned lo0, ushort_t* smemp, int tid)
{
    const int lane = tid & 63;
    const int ce = (((lane & 7) ^ ((lane >> 3) & 7)) << 3);   // swizzled elem col
    #pragma unroll
    for (int j = 0; j < 2; ++j) {
        const int rr = j * 64 + (tid >> 3);
        const ushort_t* g = G + (size_t)(rc0 + rr) * K + kt + ce;
        const unsigned lo = lo0 + (unsigned)((j * 64 + ((tid >> 3) & ~7)) * 128);
        __builtin_amdgcn_global_load_lds(
            (const __attribute__((address_space(1))) void*)g,
            (__attribute__((address_space(3))) void*)((char*)smemp + lo),
            16, 0, 0);
    }
}

#define PH_TAIL(MH, NH, BVH, VM) \
    __builtin_amdgcn_s_barrier(); \
    asm volatile("s_waitcnt lgkmcnt(0)"); \
    __builtin_amdgcn_sched_barrier(0); \
    __builtin_amdgcn_s_setprio(1); \
    mfma_quad<MH, NH>(av, BVH, acc); \
    __builtin_amdgcn_s_setprio(0); \
    __builtin_amdgcn_sched_barrier(0); \
    if (VM) asm volatile("s_waitcnt vmcnt(4)"); \
    __builtin_amdgcn_s_barrier();

__global__ __launch_bounds__(512, 2) void gemm_bf16_8ph_kernel(
    const ushort_t* __restrict__ A, const ushort_t* __restrict__ BT,
    float* __restrict__ part, int M, int N, int K, int IPC)
{
    extern __shared__ ushort_t smem8[];
    const int tid  = threadIdx.x;
    const int lane = tid & 63;
    const int wid  = tid >> 6;
    const int wm = wid >> 2, wn = wid & 3;
    const int fr = lane & 15, fq = lane >> 4;

    // grid decode + bijective XCD swizzle (T1, m204 form)
    const int gx = N >> 8, gy = M >> 8;
    const int nwg = (int)gridDim.x;
    const int q8 = nwg >> 3, r8 = nwg & 7;
    const int xcd = (int)blockIdx.x & 7, sub = (int)blockIdx.x >> 3;
    const int wg = (xcd < r8 ? xcd * (q8 + 1) : r8 * (q8 + 1) + (xcd - r8) * q8) + sub;
    const int bz  = wg / (gx * gy);
    const int rem = wg - bz * gx * gy;
    const int by  = rem / gx;
    const int bx  = rem - by * gx;
    const int row0 = by << 8, col0 = bx << 8;

    const int iters = K >> 7;                       // 128-K iterations total
    const int k0    = bz * IPC * 128;
    const int nit   = min(IPC, iters - bz * IPC);   // >= 1 by construction

    const unsigned SB  = (unsigned)(size_t)(__attribute__((address_space(3))) void*)smem8;
    const unsigned xa  = (unsigned)((fr & 7) << 4);
    const unsigned cs0 = ((unsigned)(fq * 16)) ^ xa;
    const unsigned cs1 = ((unsigned)(64 + fq * 16)) ^ xa;
    const unsigned arow = SB + (unsigned)((wm * 128 + fr) * 128);            // A region +0
    const unsigned brow = SB + 32768u + (unsigned)((wn * 64 + fr) * 128);    // B region +32K

    f32x4_t  acc[8][4] = {};
    bf16x8_t av[4][2];
    bf16x8_t bv[2][2][2];

    auto KT = [&](int tt) { int kt = k0 + tt * 64; return kt > K - 64 ? K - 64 : kt; };
    auto STA = [&](int tt, int h) {
        stage_half8(A, row0 + h * 128, K, KT(tt),
                    (unsigned)(((tt & 1) * 65536) + h * 16384), smem8, tid);
    };
    auto STB = [&](int tt, int h) {
        stage_half8(BT, col0 + h * 128, K, KT(tt),
                    (unsigned)(((tt & 1) * 65536) + 32768 + h * 16384), smem8, tid);
    };

    // ---- prologue: tile0 fully, tile1 B-halves; leave 2 half-tiles in flight
    STB(0, 0); STB(0, 1); STA(0, 0); STA(0, 1); STB(1, 0); STB(1, 1);
    asm volatile("s_waitcnt vmcnt(4)");
    __builtin_amdgcn_s_barrier();

    for (int it = 0; it < nit; ++it) {
        const int t = it << 1;
        // -------- phases 1-4: tile t from buf0 --------
        read_A8<0>(av, arow + cs0, arow + cs1);
        read_B8<0>(bv[0], brow + cs0, brow + cs1);
        STA(t + 1, 0);
        PH_TAIL(0, 0, bv[0], 0)

        read_B8<1>(bv[1], brow + cs0, brow + cs1);
        STA(t + 1, 1);
        PH_TAIL(0, 1, bv[1], 0)

        read_A8<1>(av, arow + cs0, arow + cs1);
        STB(t + 2, 0);
        PH_TAIL(1, 0, bv[0], 0)

        STB(t + 2, 1);
        PH_TAIL(1, 1, bv[1], 1)

        // -------- phases 5-8: tile t+1 from buf1 --------
        read_A8<0>(av, arow + 65536u + cs0, arow + 65536u + cs1);
        read_B8<0>(bv[0], brow + 65536u + cs0, brow + 65536u + cs1);
        STA(t + 2, 0);
        PH_TAIL(0, 0, bv[0], 0)

        read_B8<1>(bv[1], brow + 65536u + cs0, brow + 65536u + cs1);
        STA(t + 2, 1);
        PH_TAIL(0, 1, bv[1], 0)

        read_A8<1>(av, arow + 65536u + cs0, arow + 65536u + cs1);
        STB(t + 3, 0);
        PH_TAIL(1, 0, bv[0], 0)

        STB(t + 3, 1);
        PH_TAIL(1, 1, bv[1], 1)
    }

    // ---- epilogue: fp32 partials
    float* po = part + (size_t)bz * M * N;
    const int gmb = row0 + wm * 128 + fq * 4;
    const int gnb = col0 + wn * 64 + fr;
    #pragma unroll
    for (int mi = 0; mi < 8; ++mi)
        #pragma unroll
        for (int nj = 0; nj < 4; ++nj)
            #pragma unroll
            for (int r2 = 0; r2 < 4; ++r2)
                po[(size_t)(gmb + mi * 16 + r2) * N + (gnb + nj * 16)] = acc[mi][nj][r2];
}

// ---------------------------------------------------------------------------
// fp32 [R][Cin] (optional rowscale) -> bf16 [R][Cpad], zero-padded
// ---------------------------------------------------------------------------
__global__ __launch_bounds__(256) void cast_rows_kernel(
    const float* __restrict__ src, const float* __restrict__ rowscale,
    ushort_t* __restrict__ dst, int R, int Cin, int Cpad)
{
    int idx = blockIdx.x * 256 + threadIdx.x;
    if (idx >= R * Cpad) return;
    int r = idx / Cpad, c = idx - r * Cpad;
    float v = 0.0f;
    if (c < Cin) {
        v = src[(size_t)r * Cin + c];
        if (rowscale) v *= rowscale[r];
    }
    dst[idx] = f2b(v);
}

// ---------------------------------------------------------------------------
// Fused gene pre-pass: per-row inverse L2 norm + scale + cast + pad.
// One block per row. Row is read twice (2nd pass L2-hot). K%4==0.
// ---------------------------------------------------------------------------
__global__ __launch_bounds__(256) void rownorm_cast_kernel(
    const float* __restrict__ x, ushort_t* __restrict__ dst, int K, int Kpad)
{
    const int row = blockIdx.x;
    const int tid = threadIdx.x;
    const float4* xp = (const float4*)(x + (size_t)row * K);
    const int K4  = K >> 2;
    const int Kp4 = Kpad >> 2;
    float s = 0.f;
    for (int k = tid; k < K4; k += 256) {
        float4 v = xp[k];
        s += v.x * v.x + v.y * v.y + v.z * v.z + v.w * v.w;
    }
    __shared__ float red[256];
    red[tid] = s;
    __syncthreads();
    for (int o = 128; o > 0; o >>= 1) {
        if (tid < o) red[tid] += red[tid + o];
        __syncthreads();
    }
    const float inv = 1.0f / fmaxf(sqrtf(red[0]), 1e-12f);
    ushort_t* dp = dst + (size_t)row * Kpad;
    for (int k = tid; k < Kp4; k += 256) {
        float4 v = (k < K4) ? xp[k] : make_float4(0.f, 0.f, 0.f, 0.f);
        ushort_t r0 = f2b(v.x * inv), r1 = f2b(v.y * inv);
        ushort_t r2 = f2b(v.z * inv), r3 = f2b(v.w * inv);
        *(uint2*)&dp[k * 4] = make_uint2((unsigned)r0 | ((unsigned)r1 << 16),
                                         (unsigned)r2 | ((unsigned)r3 << 16));
    }
}

// ---------------------------------------------------------------------------
// fp32 W[K][N] -> bf16 WT[N][Kpad] (transpose + pad), 32x32 LDS tiles.
// Rows n in [N, Npad) are written as zeros (N-side padding for 8ph tiles).
// ---------------------------------------------------------------------------
__global__ __launch_bounds__(256) void castT_kernel(
    const float* __restrict__ W, ushort_t* __restrict__ WT,
    int K, int N, int Kpad, int Npad)
{
    __shared__ float t[32][33];
    const int nb = blockIdx.x * 32, kb = blockIdx.y * 32;
    const int x = threadIdx.x & 31, y = threadIdx.x >> 5;   // 32 x 8
    #pragma unroll
    for (int yy = 0; yy < 32; yy += 8) {
        int k = kb + y + yy, n = nb + x;
        t[y + yy][x] = (k < K && n < N) ? W[(size_t)k * N + n] : 0.0f;
    }
    __syncthreads();
    #pragma unroll
    for (int yy = 0; yy < 32; yy += 8) {
        int n = nb + y + yy, kk = kb + x;
        if (n < Npad && kk < Kpad)
            WT[(size_t)n * Kpad + kk] = (n < N) ? f2b(t[x][y + yy]) : (ushort_t)0;
    }
}

// ---------------------------------------------------------------------------
// monotone float<->uint encoding for atomicMax on floats
// ---------------------------------------------------------------------------
__device__ __forceinline__ unsigned enc_f(float f) {
    unsigned u = __float_as_uint(f);
    return (u >> 31) ? ~u : (u | 0x80000000u);
}
__device__ __forceinline__ float dec_f(unsigned e) {
    return (e >> 31) ? __uint_as_float(e ^ 0x80000000u) : __uint_as_float(~e);
}

// ---------------------------------------------------------------------------
// Fully fused GAT stage, MFMA aggregation.
// One block (256 thr) per (graph, head). h bf16 [N][H*128].
// O[d][c] = sum_s At[s][d]*h[s][c] via mfma_16x16x32_bf16:
//   A = At^T as bf16 hi/lo pair (f32-equivalent alpha precision)
//   B = h^T in chunk-XOR-swizzled LDS
// POOL=1: fused per-graph column max only.
// 16B/lane staged loads; POOL=0 output restaged via LDS for 16B stores.
// ---------------------------------------------------------------------------
// swizzled byte addr of chunk (s>>3) in row `row` of a [rows][32 bf16] region
__device__ __forceinline__ unsigned swz32(int row, int chunk) {
    return (unsigned)((row << 6) + ((chunk ^ (row & 3)) << 4));
}

template <int POOL>
__global__ __launch_bounds__(256) void gat_fused_kernel(
    const ushort_t* __restrict__ h, const int* __restrict__ esrc,
    const int* __restrict__ edst, const float* __restrict__ a_src,
    const float* __restrict__ a_dst, const float* __restrict__ bias,
    ushort_t* __restrict__ out, int H)
{
    const int g    = blockIdx.x / H;
    const int hd   = blockIdx.x % H;
    const int tid  = threadIdx.x;
    const int lane = tid & 63;
    const int wave = tid >> 6;
    const int base = g * NPG;
    const int HC   = H * CCH;

    // uni: phase A = h_row bf16 [32][128]; phase B = AtH[1024]+AtL[1024] bf16
    __shared__ __align__(16) char uni[NPG * CCH * 2];          // 8 KB
    __shared__ __align__(16) ushort_t hT[CCH * 32];            // 8 KB swizzled [c][s]
    __shared__ float At[NPG][NPG];                             // 4 KB, At[s][d]
    __shared__ float asv[CCH], adv[CCH];
    __shared__ float as_l[NPG], ad_l[NPG];
    __shared__ unsigned m_l[NPG];
    __shared__ float den_l[NPG];
    __shared__ float sc_l[EPG + NPG];
    __shared__ unsigned char s_l[EPG + NPG], d_l[EPG + NPG];

    ushort_t (*h_row)[CCH] = (ushort_t(*)[CCH])uni;
    ushort_t* AtH = (ushort_t*)uni;            // overlays h_row after its death
    ushort_t* AtL = (ushort_t*)(uni + 2048);

    // ---- hoist edge-index loads (hide HBM latency under staging) ----
    int es_r = 0, ed_r = 0;
    if (tid < EPG) {
        es_r = esrc[g * EPG + tid] - base;
        ed_r = edst[g * EPG + tid] - base;
    } else if (tid < EPG + NPG) {
        es_r = ed_r = tid - EPG;               // self-loop
    }

    // ---- stage h slice raw bf16 (16B/lane), zero At, load a-vectors ----
    const int srow = tid >> 3;                 // 0..31
    const int sch  = (tid & 7) * 16;           // elem offset, 16 elems/thread
    {
        const ushort_t* src = h + (size_t)(base + srow) * HC + hd * CCH + sch;
        uint4 v0 = *(const uint4*)(src);
        uint4 v1 = *(const uint4*)(src + 8);
        *(uint4*)&h_row[srow][sch]     = v0;
        *(uint4*)&h_row[srow][sch + 8] = v1;
    }
    #pragma unroll
    for (int i = tid; i < NPG * NPG; i += 256) ((float*)At)[i] = 0.0f;
    if (tid < CCH) asv[tid] = a_src[hd * CCH + tid];
    else           adv[tid - CCH] = a_dst[hd * CCH + tid - CCH];
    if (tid < NPG) { m_l[tid] = 0u; den_l[tid] = 0.0f; }
    __syncthreads();

    // ---- attention logits (wave-parallel shuffle reduce) ----
    for (int n = wave; n < NPG; n += 4) {
        float v0 = b2f(h_row[n][lane]), v1 = b2f(h_row[n][lane + 64]);
        float s = v0 * asv[lane] + v1 * asv[lane + 64];
        float d = v0 * adv[lane] + v1 * adv[lane + 64];
        #pragma unroll
        for (int o = 32; o > 0; o >>= 1) {
            s += __shfl_xor(s, o, 64);
            d += __shfl_xor(d, o, 64);
        }
        if (lane == 0) { as_l[n] = s; ad_l[n] = d; }
    }
    // ---- transpose h_row -> hT (swizzled); thread owns col c, rows s0..s0+15
    {
        const int c  = tid & 127;
        const int s0 = (tid >> 7) * 16;        // 0 or 16
        #pragma unroll
        for (int hh = 0; hh < 2; ++hh) {
            const int sb = s0 + hh * 8;
            unsigned pk[4];
            #pragma unroll
            for (int p = 0; p < 4; ++p) {
                unsigned lo = h_row[sb + 2 * p][c];
                unsigned hi = h_row[sb + 2 * p + 1][c];
                pk[p] = lo | (hi << 16);
            }
            *(uint4*)((char*)hT + swz32(c, sb >> 3)) = make_uint4(pk[0], pk[1], pk[2], pk[3]);
        }
    }
    __syncthreads();

    // ---- edge scores + segment max ----
    if (tid < EPG + NPG) {
        float e = as_l[es_r] + ad_l[ed_r];
        e = (e >= 0.0f) ? e : 0.2f * e;        // leaky_relu 0.2
        sc_l[tid] = e;
        s_l[tid] = (unsigned char)es_r;
        d_l[tid] = (unsigned char)ed_r;
        atomicMax(&m_l[ed_r], enc_f(e));
    }
    __syncthreads();

    // ---- exp + segment sum ----
    if (tid < EPG + NPG) {
        float ex = expf(sc_l[tid] - dec_f(m_l[d_l[tid]]));
        sc_l[tid] = ex;
        atomicAdd(&den_l[d_l[tid]], ex);
    }
    __syncthreads();

    // ---- scatter alpha into dense At[s][d] ----
    if (tid < EPG + NPG) {
        float al = sc_l[tid] / (den_l[d_l[tid]] + 1e-16f);
        atomicAdd(&At[s_l[tid]][d_l[tid]], al);
    }
    __syncthreads();

    // ---- At[s][d] -> At^T hi/lo bf16 rows (h_row dead; AtH/AtL overlay) ---
    {
        const int d  = tid >> 3;               // 0..31
        const int s4 = (tid & 7) * 4;          // 0,4,..,28
        float v0 = At[s4 + 0][d], v1 = At[s4 + 1][d];
        float v2 = At[s4 + 2][d], v3 = At[s4 + 3][d];
        ushort_t h0 = f2b(v0), h1 = f2b(v1), h2 = f2b(v2), h3 = f2b(v3);
        ushort_t l0 = f2b(v0 - b2f(h0)), l1 = f2b(v1 - b2f(h1));
        ushort_t l2 = f2b(v2 - b2f(h2)), l3 = f2b(v3 - b2f(h3));
        const unsigned a = swz32(d, s4 >> 3) + (unsigned)((s4 & 7) * 2);
        *(uint2*)((char*)AtH + a) = make_uint2((unsigned)h0 | ((unsigned)h1 << 16),
                                               (unsigned)h2 | ((unsigned)h3 << 16));
        *(uint2*)((char*)AtL + a) = make_uint2((unsigned)l0 | ((unsigned)l1 << 16),
                                               (unsigned)l2 | ((unsigned)l3 << 16));
    }
    __syncthreads();

    // ---- MFMA aggregation: per wave 1 d-block x 4 c-tiles, hi+lo ----
    const int fr = lane & 15, fq = lane >> 4;
    const int dblk  = wave & 1;
    const int cbase = (wave >> 1) * 64;

    bf16x8_t aH = *(const bf16x8_t*)((char*)AtH + swz32(dblk * 16 + fr, fq));
    bf16x8_t aL = *(const bf16x8_t*)((char*)AtL + swz32(dblk * 16 + fr, fq));
    bf16x8_t bfr[4];
    #pragma unroll
    for (int q = 0; q < 4; ++q)
        bfr[q] = *(const bf16x8_t*)((char*)hT + swz32(cbase + q * 16 + fr, fq));

    if (!POOL) __syncthreads();                // all hT reads done before reuse

    f32x4_t acc[4] = {};
    #pragma unroll
    for (int q = 0; q < 4; ++q) {
        acc[q] = __builtin_amdgcn_mfma_f32_16x16x32_bf16(aH, bfr[q], acc[q], 0, 0, 0);
        acc[q] = __builtin_amdgcn_mfma_f32_16x16x32_bf16(aL, bfr[q], acc[q], 0, 0, 0);
    }

    if (POOL) {
        float* pool2 = (float*)At;             // At dead; needs 256 floats
        #pragma unroll
        for (int q = 0; q < 4; ++q) {
            const int c = cbase + q * 16 + fr;
            const float bb = bias[hd * CCH + c];
            float m = -INFINITY;
            #pragma unroll
            for (int r = 0; r < 4; ++r) {
                float v = acc[q][r] + bb;
                v = (v > 0.0f) ? v : (expf(v) - 1.0f);
                m = fmaxf(m, v);
            }
            m = fmaxf(m, __shfl_xor(m, 16, 64));
            m = fmaxf(m, __shfl_xor(m, 32, 64));
            if (fq == 0) pool2[dblk * CCH + c] = m;
        }
        __syncthreads();
        if (tid < CCH)
            out[(size_t)g * CCH + tid] = f2b(fmaxf(pool2[tid], pool2[CCH + tid]));
    } else {
        // restage output tile in LDS (hT region, dead) for coalesced stores
        ushort_t (*o_l)[CCH] = (ushort_t(*)[CCH])hT;
        #pragma unroll
        for (int q = 0; q < 4; ++q) {
            const int c = cbase + q * 16 + fr;
            const float bb = bias[hd * CCH + c];
            #pragma unroll
            for (int r = 0; r < 4; ++r) {
                float v = acc[q][r] + bb;
                v = (v > 0.0f) ? v : (expf(v) - 1.0f);
                o_l[dblk * 16 + fq * 4 + r][c] = f2b(v);
            }
        }
        __syncthreads();
        ushort_t* dst = out + (size_t)(base + srow) * HC + hd * CCH + sch;
        *(uint4*)(dst)     = *(const uint4*)&o_l[srow][sch];
        *(uint4*)(dst + 8) = *(const uint4*)&o_l[srow][sch + 8];
    }
}

// ---------------------------------------------------------------------------
// Column-block copy helper (into concat buffers), strided src
// ---------------------------------------------------------------------------
__global__ __launch_bounds__(256) void copyb_kernel(
    ushort_t* __restrict__ dst, int dld, int doff,
    const ushort_t* __restrict__ src, int sld, int rows, int cols)
{
    int idx = blockIdx.x * 256 + threadIdx.x;
    if (idx >= rows * cols) return;
    int r = idx / cols, c = idx - r * cols;
    dst[(size_t)r * dld + doff + c] = src[(size_t)r * sld + c];
}

__global__ __launch_bounds__(256) void castcols_kernel(
    ushort_t* __restrict__ dst, int ld, int off,
    const float* __restrict__ src, int rows, int cols)
{
    int idx = blockIdx.x * 256 + threadIdx.x;
    if (idx >= rows * cols) return;
    int r = idx / cols, c = idx - r * cols;
    dst[(size_t)r * ld + off + c] = f2b(src[idx]);
}

// ---------------------------------------------------------------------------
// Final N_TASKS=1: out[b] = y[b,:256] . w + bout   (y bf16)
// ---------------------------------------------------------------------------
__global__ __launch_bounds__(256) void final_kernel(
    const ushort_t* __restrict__ y, const float* __restrict__ w,
    const float* __restrict__ b, float* __restrict__ out)
{
    const int row = blockIdx.x;
    const int tid = threadIdx.x;
    float v = b2f(y[(size_t)row * 256 + tid]) * w[tid];
    __shared__ float red[256];
    red[tid] = v;
    __syncthreads();
    for (int o = 128; o > 0; o >>= 1) {
        if (tid < o) red[tid] += red[tid + o];
        __syncthreads();
    }
    if (tid == 0) out[row] = red[0] + b[0];
}

// ---------------------------------------------------------------------------
// Host side
// ---------------------------------------------------------------------------
static inline void launch_gemm(const ushort_t* A, const ushort_t* BT,
                               const float* bias, ushort_t* C,
                               int M, int N, int K, int act, hipStream_t stream)
{
    dim3 grid(N / GBN, M / GBM);
    gemm_bf16_kernel<<<grid, 256, 0, stream>>>(A, BT, bias, C, M, N, K, act);
}

// split-K GEMM: partials into `part` (fp32), then reduce with bias+act
static inline void launch_gemm_sk(const ushort_t* A, const ushort_t* BT,
                                  const float* bias, ushort_t* C, float* part,
                                  int M, int N, int K, int S, int act,
                                  hipStream_t stream,
                                  int Nb = -1, int Cld = -1, int Coff = 0)
{
    if (Nb  < 0) Nb  = N;
    if (Cld < 0) Cld = N;
    const int iters = K / GBK;
    const int ipc   = (iters + S - 1) / S;         // iters per chunk
    const int S_eff = (iters + ipc - 1) / ipc;     // no empty chunks
    const int KC    = ipc * GBK;
    dim3 grid(N / GBN, M / GBM, S_eff);
    gemm_bf16_part_kernel<<<grid, 256, 0, stream>>>(A, BT, part, M, N, K, KC);
    const int MN = M * N;
    reduce_kernel<<<(MN / 4 + 255) / 256, 256, 0, stream>>>(
        part, bias, C, MN, N, S_eff, act, Nb, Cld, Coff);
}

// 8-phase 256^2 split-K GEMM path (M%256==0, N%256==0, K%128==0)
static inline void launch_gemm_8ph(const ushort_t* A, const ushort_t* BT,
                                   const float* bias, ushort_t* C, float* part,
                                   int M, int N, int K, int S, int act,
                                   hipStream_t stream,
                                   int Nb = -1, int Cld = -1, int Coff = 0)
{
    if (Nb  < 0) Nb  = N;
    if (Cld < 0) Cld = N;
    const int iters = K >> 7;                      // 128-K iterations
    const int ipc   = (iters + S - 1) / S;
    const int S_eff = (iters + ipc - 1) / ipc;
    const int gx = N >> 8, gy = M >> 8;
    const int nwg = gx * gy * S_eff;
    static bool attr_done = false;
    if (!attr_done) {
        (void)hipFuncSetAttribute((const void*)gemm_bf16_8ph_kernel,
                                  hipFuncAttributeMaxDynamicSharedMemorySize, 131072);
        attr_done = true;
    }
    gemm_bf16_8ph_kernel<<<dim3(nwg), 512, 131072, stream>>>(A, BT, part, M, N, K, ipc);
    const int MN = M * N;
    reduce_kernel<<<(MN / 4 + 255) / 256, 256, 0, stream>>>(
        part, bias, C, MN, N, S_eff, act, Nb, Cld, Coff);
}

static inline void launch_castT(const float* W, ushort_t* WT, int K, int N,
                                int Kpad, hipStream_t stream, int Npad = -1)
{
    if (Npad < 0) Npad = N;
    dim3 grid((Npad + 31) / 32, (Kpad + 31) / 32);
    castT_kernel<<<grid, 256, 0, stream>>>(W, WT, K, N, Kpad, Npad);
}

extern "C" void kernel_launch(void* const* d_in, const int* in_sizes, int n_in,
                              void* d_out, int out_size, void* d_ws, size_t ws_size,
                              hipStream_t stream)
{
    const float* x1      = (const float*)d_in[0];
    const float* x2      = (const float*)d_in[1];
    const float* gene    = (const float*)d_in[2];
    const float* drr     = (const float*)d_in[3];
    const float* drc     = (const float*)d_in[4];
    const float* prot    = (const float*)d_in[5];
    const int*   ei1     = (const int*)d_in[6];
    const int*   ei2     = (const int*)d_in[7];
    const float* W_gat1  = (const float*)d_in[9];
    const float* b_gat1  = (const float*)d_in[10];
    const float* a_src1  = (const float*)d_in[11];
    const float* a_dst1  = (const float*)d_in[12];
    const float* W_gat2  = (const float*)d_in[13];
    const float* b_gat2  = (const float*)d_in[14];
    const float* a_src2  = (const float*)d_in[15];
    const float* a_dst2  = (const float*)d_in[16];
    const float* W_fcg   = (const float*)d_in[17];
    const float* b_fcg   = (const float*)d_in[18];
    const float* Wr1     = (const float*)d_in[19];
    const float* br1     = (const float*)d_in[20];
    const float* Wr2     = (const float*)d_in[21];
    const float* br2     = (const float*)d_in[22];
    const float* Wr3     = (const float*)d_in[23];
    const float* br3     = (const float*)d_in[24];
    const float* Wp1     = (const float*)d_in[25];
    const float* bp1     = (const float*)d_in[26];
    const float* Wp2     = (const float*)d_in[27];
    const float* bp2     = (const float*)d_in[28];
    const float* Wp3     = (const float*)d_in[29];
    const float* bp3     = (const float*)d_in[30];
    const float* Wdrr    = (const float*)d_in[31];
    const float* bdrr    = (const float*)d_in[32];
    const float* Wdrc    = (const float*)d_in[33];
    const float* bdrc    = (const float*)d_in[34];
    const float* Wf1     = (const float*)d_in[35];
    const float* bf1     = (const float*)d_in[36];
    const float* Wf2     = (const float*)d_in[37];
    const float* bf2     = (const float*)d_in[38];
    const float* Wout    = (const float*)d_in[39];
    const float* bout    = (const float*)d_in[40];
    float* outp = (float*)d_out;

    char* ws = (char*)d_ws;
    size_t off = 0;
    auto alloc = [&](size_t bytes) -> char* {
        char* r = ws + off;
        off += (bytes + 255) & ~(size_t)255;
        return r;
    };

    char* BIG0 = alloc(134217728);
    char* BIG1 = alloc(67108864);

    ushort_t* go1f   = (ushort_t*)BIG0;
    ushort_t* h1     = (ushort_t*)BIG1;
    float*    part   = (float*)BIG1;
    ushort_t* WT_r1  = (ushort_t*)(BIG0 + 0);           // 2048x18048 = 73,924,608
    ushort_t* gene_nb= (ushort_t*)(BIG0 + 73924608);    // 1024x18048 = 36,962,304
    ushort_t* cell1  = (ushort_t*)(BIG0 + 110886912);   // 1024x2048  =  4,194,304
    ushort_t* WT_r2  = (ushort_t*)(BIG0 + 115081216);   // 512x2048   =  2,097,152
    ushort_t* WT_p2  = (ushort_t*)(BIG0 + 117178368);   // 512x1024   =  1,048,576
    ushort_t* WT_p1  = (ushort_t*)(BIG0 + 118226944);   // 1024x6784  = 13,895,680

    ushort_t* xb     = (ushort_t*)alloc((size_t)NNODES * 96 * 2);        // per-drug
    char*     h2reg  = alloc((size_t)2 * NNODES * 128 * 2);              // 16.8 MB
    char*     catreg = alloc((size_t)2 * 1024 * 2176 * 2);               //  8.9 MB
    ushort_t* h2f    = (ushort_t*)h2reg;     // drug phase
    ushort_t* protb  = (ushort_t*)h2reg;     // MLP phase alias (13.9 MB <= 16.8)
    ushort_t* cat1   = (ushort_t*)catreg;
    ushort_t* cat2   = (ushort_t*)(catreg + (size_t)1024 * 2176 * 2);
    ushort_t* pooled = (ushort_t*)alloc((size_t)2 * BATCH * 128 * 2);
    ushort_t* gpair  = (ushort_t*)alloc((size_t)2 * BATCH * 128 * 2);
    ushort_t* y1     = (ushort_t*)alloc((size_t)BATCH * 512 * 2);
    ushort_t* y2     = (ushort_t*)alloc((size_t)BATCH * 256 * 2);
    ushort_t* WT_g1  = (ushort_t*)alloc((size_t)1024 * 96 * 2);
    ushort_t* WT_g2  = (ushort_t*)alloc((size_t)128 * 1024 * 2);
    ushort_t* WT_fcg = (ushort_t*)alloc((size_t)128 * 128 * 2);
    ushort_t* WT_r3  = (ushort_t*)alloc((size_t)256 * 512 * 2);
    ushort_t* WT_p3  = (ushort_t*)alloc((size_t)256 * 512 * 2);
    ushort_t* WT_f2  = (ushort_t*)alloc((size_t)256 * 512 * 2);
    ushort_t* WT_drr = (ushort_t*)alloc((size_t)2304 * 2176 * 2);   // N padded
    ushort_t* WT_drc = (ushort_t*)alloc((size_t)2304 * 2176 * 2);   // N padded
    ushort_t* WT_f1  = (ushort_t*)alloc((size_t)512 * 4864 * 2);
    ushort_t* p1b    = (ushort_t*)alloc((size_t)1024 * 1024 * 2);
    ushort_t* p2b    = (ushort_t*)alloc((size_t)1024 * 512 * 2);
    ushort_t* cell2  = (ushort_t*)alloc((size_t)1024 * 512 * 2);
    ushort_t* ybuf   = (ushort_t*)alloc((size_t)1024 * 4864 * 2);

    const int E = in_sizes[6] / 2;   // 131072

    // ---------------- drug-phase weight casts ----------------
    launch_castT(W_gat1, WT_g1, INFEAT, 1024, 96, stream);
    launch_castT(W_gat2, WT_g2, 1024, 128, 1024, stream);
    launch_castT(W_fcg,  WT_fcg, 128, 128, 128, stream);

    // ---------------- drug branch: GAT1 per drug, write into shared go1f ---
    for (int drug = 0; drug < 2; drug++) {
        const float* x  = drug ? x2 : x1;
        const int*   es = (drug ? ei2 : ei1);
        const int*   ed = es + E;
        ushort_t* go1d = go1f + (size_t)drug * NNODES * 1024;

        cast_rows_kernel<<<(NNODES * 96 + 255) / 256, 256, 0, stream>>>(
            x, nullptr, xb, NNODES, INFEAT, 96);
        launch_gemm(xb, WT_g1, nullptr, h1, NNODES, 1024, 96, ACT_NONE, stream);
        gat_fused_kernel<0><<<BATCH * NHEAD, 256, 0, stream>>>(
            h1, es, ed, a_src1, a_dst1, b_gat1, go1d, NHEAD);
    }

    // ---------------- batched GAT2 GEMM (M=65536 -> 512 blocks) ------------
    launch_gemm(go1f, WT_g2, nullptr, h2f, 2 * NNODES, 128, 1024, ACT_NONE, stream);

    // BIG0 (go1f) now dead -> cast MLP-phase weights into it
    launch_castT(Wr1, WT_r1, GENE, 2048, GENEP, stream);
    launch_castT(Wr2, WT_r2, 2048, 512, 2048, stream);
    launch_castT(Wp1, WT_p1, PROT, 1024, PROTP, stream);
    launch_castT(Wp2, WT_p2, 1024, 512, 1024, stream);
    launch_castT(Wr3, WT_r3, 512, 256, 512, stream);
    launch_castT(Wp3, WT_p3, 512, 256, 512, stream);
    launch_castT(Wf2, WT_f2, 512, 256, 512, stream);
    launch_castT(Wdrr, WT_drr, 2176, 2176, 2176, stream, 2304);
    launch_castT(Wdrc, WT_drc, 2176, 2176, 2176, stream, 2304);
    launch_castT(Wf1, WT_f1, 4864, 512, 4864, stream);

    // ---------------- GAT2 fused (attn + softmax + agg + maxpool) ----------
    for (int drug = 0; drug < 2; drug++) {
        const int* es = (drug ? ei2 : ei1);
        const int* ed = es + E;
        gat_fused_kernel<1><<<BATCH, 256, 0, stream>>>(
            h2f + (size_t)drug * NNODES * 128, es, ed,
            a_src2, a_dst2, b_gat2, pooled + (size_t)drug * BATCH * 128, 1);
    }
    launch_gemm(pooled, WT_fcg, b_fcg, gpair, 2 * BATCH, 128, 128, ACT_RELU, stream);

    // ---------------- gene branch (fused norm+cast, 8-phase big-K GEMM) ----
    rownorm_cast_kernel<<<BATCH, 256, 0, stream>>>(gene, gene_nb, GENE, GENEP);
    launch_gemm_8ph(gene_nb, WT_r1, br1, cell1, part, BATCH, 2048, GENEP, 8, ACT_RELU, stream);
    launch_gemm_sk(cell1, WT_r2, br2, cell2, part, BATCH, 512, 2048, 8, ACT_RELU, stream);
    launch_gemm_sk(cell2, WT_r3, br3, ybuf, part, BATCH, 256, 512, 4, ACT_RELU, stream,
                   256, 4864, 4352);

    // ---------------- protein branch (8-phase for K=6784; protb aliases h2f)
    cast_rows_kernel<<<(BATCH * PROTP + 255) / 256, 256, 0, stream>>>(
        prot, nullptr, protb, BATCH, PROT, PROTP);
    launch_gemm_8ph(protb, WT_p1, bp1, p1b, part, BATCH, 1024, PROTP, 16, ACT_ELU, stream);
    launch_gemm_sk(p1b, WT_p2, bp2, p2b, part, BATCH, 512, 1024, 4, ACT_ELU, stream);
    launch_gemm_sk(p2b, WT_p3, bp3, ybuf, part, BATCH, 256, 512, 4, ACT_RELU, stream,
                   256, 4864, 4608);

    // ---------------- fingerprint fusion (8-phase, write into ybuf) --------
    {
        int n = BATCH * CCH;
        copyb_kernel<<<(n + 255) / 256, 256, 0, stream>>>(cat1, 2176, 0, gpair, 128, BATCH, CCH);
        copyb_kernel<<<(n + 255) / 256, 256, 0, stream>>>(cat2, 2176, 0, gpair + BATCH * CCH, 128, BATCH, CCH);
        n = BATCH * FPD;
        castcols_kernel<<<(n + 255) / 256, 256, 0, stream>>>(cat1, 2176, CCH, drr, BATCH, FPD);
        castcols_kernel<<<(n + 255) / 256, 256, 0, stream>>>(cat2, 2176, CCH, drc, BATCH, FPD);
    }
    launch_gemm_8ph(cat1, WT_drr, bdrr, ybuf, part, BATCH, 2304, 2176, 7, ACT_RELU, stream,
                    2176, 4864, 0);
    launch_gemm_8ph(cat2, WT_drc, bdrc, ybuf, part, BATCH, 2304, 2176, 7, ACT_RELU, stream,
                    2176, 4864, 2176);

    // ---------------- predictor ----------------
    launch_gemm_sk(ybuf, WT_f1, bf1, y1, part, BATCH, 512, 4864, 8, ACT_RELU, stream);
    launch_gemm_sk(y1, WT_f2, bf2, y2, part, BATCH, 256, 512, 4, ACT_RELU, stream);
    final_kernel<<<BATCH, 256, 0, stream>>>(y2, Wout, bout, outp);
}

// Round 4
// 1017.371 us; speedup vs baseline: 1.2349x; 1.0634x over previous
//
#include <hip/hip_runtime.h>
#include <math.h>

// ---------------------------------------------------------------------------
// Model dims (fixed by the reference)
// ---------------------------------------------------------------------------
#define BATCH   1024
#define NPG     32
#define NNODES  (BATCH * NPG)      // 32768 per drug
#define EPG     128
#define INFEAT  78
#define CCH     128
#define NHEAD   8
#define GENE    18000
#define GENEP   18048              // padded to %128 (8-phase kernel needs K%128)
#define PROT    6688
#define PROTP   6784               // padded to %128
#define FPD     2048

#define ACT_NONE 0
#define ACT_RELU 1
#define ACT_ELU  2

typedef unsigned short ushort_t;
typedef __bf16 bf16x8_t __attribute__((ext_vector_type(8)));
typedef float  f32x4_t  __attribute__((ext_vector_type(4)));

__device__ __forceinline__ float b2f(ushort_t u) {
    return __uint_as_float(((unsigned)u) << 16);
}
__device__ __forceinline__ ushort_t f2b(float f) {
    unsigned x = __float_as_uint(f);
    return (ushort_t)((x + 0x7fffu + ((x >> 16) & 1u)) >> 16);   // RNE
}

// ---------------------------------------------------------------------------
// bf16 MFMA GEMM (m97 structure): C[M,N] = act(A[M,K] @ BT[N,K]^T + bias)
// A, BT bf16 (K%32==0); C bf16; bias fp32. M%128==0, N%128==0.
// 128x128 tile, BK=32, 256 threads (2x2 waves of 64x64), global_load_lds.
// ---------------------------------------------------------------------------
#define GBM 128
#define GBN 128
#define GBK 32

__device__ __forceinline__ void gemm_core(
    const ushort_t* __restrict__ A, const ushort_t* __restrict__ BT,
    int K, int kb, int ke, int row0, int col0,
    ushort_t* Asl, ushort_t* Bsl, f32x4_t acc[4][4])
{
    const int tid  = threadIdx.x;
    const int wave = tid >> 6;
    const int lane = tid & 63;
    const int wr   = wave >> 1;
    const int wc   = wave & 1;
    const int srow = lane >> 2;        // 0..15
    const int skel = (lane & 3) * 8;   // bf16 elem offset

    for (int k0 = kb; k0 < ke; k0 += GBK) {
        __syncthreads();               // protect LDS from previous iteration
        #pragma unroll
        for (int t = 0; t < 2; ++t) {
            const int rg = wave * 32 + t * 16;                   // wave-uniform
            const ushort_t* ga = A + (size_t)(row0 + rg + srow) * K + k0 + skel;
            __builtin_amdgcn_global_load_lds(
                (const __attribute__((address_space(1))) void*)ga,
                (__attribute__((address_space(3))) void*)&Asl[rg * GBK], 16, 0, 0);
            const ushort_t* gb = BT + (size_t)(col0 + rg + srow) * K + k0 + skel;
            __builtin_amdgcn_global_load_lds(
                (const __attribute__((address_space(1))) void*)gb,
                (__attribute__((address_space(3))) void*)&Bsl[rg * GBK], 16, 0, 0);
        }
        __syncthreads();

        const int fr = lane & 15;
        const int fq = lane >> 4;
        bf16x8_t av[4], bv[4];
        #pragma unroll
        for (int i = 0; i < 4; ++i)
            av[i] = *(const bf16x8_t*)&Asl[(wr * 64 + i * 16 + fr) * GBK + fq * 8];
        #pragma unroll
        for (int j = 0; j < 4; ++j)
            bv[j] = *(const bf16x8_t*)&Bsl[(wc * 64 + j * 16 + fr) * GBK + fq * 8];
        #pragma unroll
        for (int i = 0; i < 4; ++i)
            #pragma unroll
            for (int j = 0; j < 4; ++j)
                acc[i][j] = __builtin_amdgcn_mfma_f32_16x16x32_bf16(
                    av[i], bv[j], acc[i][j], 0, 0, 0);
    }
}

__global__ __launch_bounds__(256) void gemm_bf16_kernel(
    const ushort_t* __restrict__ A, const ushort_t* __restrict__ BT,
    const float* __restrict__ bias, ushort_t* __restrict__ C,
    int M, int N, int K, int act)
{
    __shared__ ushort_t Asl[GBM * GBK];
    __shared__ ushort_t Bsl[GBN * GBK];
    const int lane = threadIdx.x & 63;
    const int wave = threadIdx.x >> 6;
    const int wr = wave >> 1, wc = wave & 1;
    const int row0 = blockIdx.y * GBM;
    const int col0 = blockIdx.x * GBN;

    f32x4_t acc[4][4] = {};
    gemm_core(A, BT, K, 0, K, row0, col0, Asl, Bsl, acc);

    const int fr = lane & 15;
    const int fq = lane >> 4;
    #pragma unroll
    for (int i = 0; i < 4; ++i) {
        #pragma unroll
        for (int j = 0; j < 4; ++j) {
            const int gn = col0 + wc * 64 + j * 16 + fr;
            const float bb = bias ? bias[gn] : 0.0f;
            #pragma unroll
            for (int r = 0; r < 4; ++r) {
                const int gm = row0 + wr * 64 + i * 16 + fq * 4 + r;
                float v = acc[i][j][r] + bb;
                if (act == ACT_RELU)     v = fmaxf(v, 0.0f);
                else if (act == ACT_ELU) v = (v > 0.0f) ? v : (expf(v) - 1.0f);
                C[(size_t)gm * N + gn] = f2b(v);
            }
        }
    }
}

// split-K variant: grid.z = chunk index, fp32 partials out (no bias/act)
__global__ __launch_bounds__(256) void gemm_bf16_part_kernel(
    const ushort_t* __restrict__ A, const ushort_t* __restrict__ BT,
    float* __restrict__ part, int M, int N, int K, int KC)
{
    __shared__ ushort_t Asl[GBM * GBK];
    __shared__ ushort_t Bsl[GBN * GBK];
    const int lane = threadIdx.x & 63;
    const int wave = threadIdx.x >> 6;
    const int wr = wave >> 1, wc = wave & 1;
    const int row0 = blockIdx.y * GBM;
    const int col0 = blockIdx.x * GBN;
    const int z    = blockIdx.z;
    const int kb   = z * KC;
    const int ke   = min(K, kb + KC);

    f32x4_t acc[4][4] = {};
    gemm_core(A, BT, K, kb, ke, row0, col0, Asl, Bsl, acc);

    const int fr = lane & 15;
    const int fq = lane >> 4;
    float* po = part + (size_t)z * M * N;
    #pragma unroll
    for (int i = 0; i < 4; ++i)
        #pragma unroll
        for (int j = 0; j < 4; ++j) {
            const int gn = col0 + wc * 64 + j * 16 + fr;
            #pragma unroll
            for (int r = 0; r < 4; ++r) {
                const int gm = row0 + wr * 64 + i * 16 + fq * 4 + r;
                po[(size_t)gm * N + gn] = acc[i][j][r];
            }
        }
}

// sum S partials + bias + act -> bf16 written at C[r*Cld + Coff + n], n < Nb
__global__ __launch_bounds__(256) void reduce_kernel(
    const float* __restrict__ part, const float* __restrict__ bias,
    ushort_t* __restrict__ C, int MN, int N, int S, int act,
    int Nb, int Cld, int Coff)
{
    int i4 = (blockIdx.x * 256 + threadIdx.x) * 4;
    if (i4 >= MN) return;
    const int r = i4 / N, n = i4 - r * N;
    if (n >= Nb) return;                    // zero-padded cols: no store
    float4 s = *(const float4*)&part[i4];
    for (int z = 1; z < S; ++z) {
        float4 v = *(const float4*)&part[(size_t)z * MN + i4];
        s.x += v.x; s.y += v.y; s.z += v.z; s.w += v.w;
    }
    float o[4] = { s.x, s.y, s.z, s.w };
    if (bias) { o[0] += bias[n]; o[1] += bias[n+1]; o[2] += bias[n+2]; o[3] += bias[n+3]; }
    ushort_t rr[4];
    #pragma unroll
    for (int k = 0; k < 4; ++k) {
        float v = o[k];
        if (act == ACT_RELU)     v = fmaxf(v, 0.0f);
        else if (act == ACT_ELU) v = (v > 0.0f) ? v : (expf(v) - 1.0f);
        rr[k] = f2b(v);
    }
    unsigned pk0 = (unsigned)rr[0] | ((unsigned)rr[1] << 16);
    unsigned pk1 = (unsigned)rr[2] | ((unsigned)rr[3] << 16);
    *(uint2*)&C[(size_t)r * Cld + Coff + n] = make_uint2(pk0, pk1);
}

// ---------------------------------------------------------------------------
// 8-phase 256x256 split-K GEMM (T1+T2+T3+T4+T5), for big-K skinny GEMMs.
// part[z][M][N] fp32 = A[M,K] @ BT[N,K]^T over K-chunk z.
// Requirements: M%256==0, N%256==0, K%128==0.
// ---------------------------------------------------------------------------
#define DSREAD(dst, addr) asm volatile("ds_read_b128 %0, %1" : "=v"(dst) : "v"(addr))

template <int MH>
__device__ __forceinline__ void read_A8(bf16x8_t (&av)[4][2], unsigned b0, unsigned b1)
{
    DSREAD(av[0][0], b0 + (MH * 4 + 0) * 2048);
    DSREAD(av[0][1], b1 + (MH * 4 + 0) * 2048);
    DSREAD(av[1][0], b0 + (MH * 4 + 1) * 2048);
    DSREAD(av[1][1], b1 + (MH * 4 + 1) * 2048);
    DSREAD(av[2][0], b0 + (MH * 4 + 2) * 2048);
    DSREAD(av[2][1], b1 + (MH * 4 + 2) * 2048);
    DSREAD(av[3][0], b0 + (MH * 4 + 3) * 2048);
    DSREAD(av[3][1], b1 + (MH * 4 + 3) * 2048);
}

template <int NH>
__device__ __forceinline__ void read_B8(bf16x8_t (&bvh)[2][2], unsigned b0, unsigned b1)
{
    DSREAD(bvh[0][0], b0 + (NH * 2 + 0) * 2048);
    DSREAD(bvh[0][1], b1 + (NH * 2 + 0) * 2048);
    DSREAD(bvh[1][0], b0 + (NH * 2 + 1) * 2048);
    DSREAD(bvh[1][1], b1 + (NH * 2 + 1) * 2048);
}

template <int MH, int NH>
__device__ __forceinline__ void mfma_quad(const bf16x8_t (&av)[4][2],
                                          const bf16x8_t (&bvh)[2][2],
                                          f32x4_t (&acc)[8][4])
{
    #pragma unroll
    for (int qq = 0; qq < 4; ++qq)
        #pragma unroll
        for (int pp = 0; pp < 2; ++pp)
            #pragma unroll
            for (int ss = 0; ss < 2; ++ss)
                acc[MH * 4 + qq][NH * 2 + pp] = __builtin_amdgcn_mfma_f32_16x16x32_bf16(
                    av[qq][ss], bvh[pp][ss], acc[MH * 4 + qq][NH * 2 + pp], 0, 0, 0);
}

// stage one 128-row x 64-col half-tile (2 x global_load_lds of 16B per thread)
__device__ __forceinline__ void stage_half8(
    const ushort_t* __restrict__ G, int rc0, int K, int kt,
    unsigned lo0, ushort_t* smemp, int tid)
{
    const int lane = tid & 63;
    const int ce = (((lane & 7) ^ ((lane >> 3) & 7)) << 3);   // swizzled elem col
    #pragma unroll
    for (int j = 0; j < 2; ++j) {
        const int rr = j * 64 + (tid >> 3);
        const ushort_t* g = G + (size_t)(rc0 + rr) * K + kt + ce;
        const unsigned lo = lo0 + (unsigned)((j * 64 + ((tid >> 3) & ~7)) * 128);
        __builtin_amdgcn_global_load_lds(
            (const __attribute__((address_space(1))) void*)g,
            (__attribute__((address_space(3))) void*)((char*)smemp + lo),
            16, 0, 0);
    }
}

#define PH_TAIL(MH, NH, BVH, VM) \
    __builtin_amdgcn_s_barrier(); \
    asm volatile("s_waitcnt lgkmcnt(0)"); \
    __builtin_amdgcn_sched_barrier(0); \
    __builtin_amdgcn_s_setprio(1); \
    mfma_quad<MH, NH>(av, BVH, acc); \
    __builtin_amdgcn_s_setprio(0); \
    __builtin_amdgcn_sched_barrier(0); \
    if (VM) asm volatile("s_waitcnt vmcnt(4)"); \
    __builtin_amdgcn_s_barrier();

__global__ __launch_bounds__(512, 2) void gemm_bf16_8ph_kernel(
    const ushort_t* __restrict__ A, const ushort_t* __restrict__ BT,
    float* __restrict__ part, int M, int N, int K, int IPC)
{
    extern __shared__ ushort_t smem8[];
    const int tid  = threadIdx.x;
    const int lane = tid & 63;
    const int wid  = tid >> 6;
    const int wm = wid >> 2, wn = wid & 3;
    const int fr = lane & 15, fq = lane >> 4;

    // grid decode + bijective XCD swizzle (T1, m204 form)
    const int gx = N >> 8, gy = M >> 8;
    const int nwg = (int)gridDim.x;
    const int q8 = nwg >> 3, r8 = nwg & 7;
    const int xcd = (int)blockIdx.x & 7, sub = (int)blockIdx.x >> 3;
    const int wg = (xcd < r8 ? xcd * (q8 + 1) : r8 * (q8 + 1) + (xcd - r8) * q8) + sub;
    const int bz  = wg / (gx * gy);
    const int rem = wg - bz * gx * gy;
    const int by  = rem / gx;
    const int bx  = rem - by * gx;
    const int row0 = by << 8, col0 = bx << 8;

    const int iters = K >> 7;                       // 128-K iterations total
    const int k0    = bz * IPC * 128;
    const int nit   = min(IPC, iters - bz * IPC);   // >= 1 by construction

    const unsigned SB  = (unsigned)(size_t)(__attribute__((address_space(3))) void*)smem8;
    const unsigned xa  = (unsigned)((fr & 7) << 4);
    const unsigned cs0 = ((unsigned)(fq * 16)) ^ xa;
    const unsigned cs1 = ((unsigned)(64 + fq * 16)) ^ xa;
    const unsigned arow = SB + (unsigned)((wm * 128 + fr) * 128);            // A region +0
    const unsigned brow = SB + 32768u + (unsigned)((wn * 64 + fr) * 128);    // B region +32K

    f32x4_t  acc[8][4] = {};
    bf16x8_t av[4][2];
    bf16x8_t bv[2][2][2];

    auto KT = [&](int tt) { int kt = k0 + tt * 64; return kt > K - 64 ? K - 64 : kt; };
    auto STA = [&](int tt, int h) {
        stage_half8(A, row0 + h * 128, K, KT(tt),
                    (unsigned)(((tt & 1) * 65536) + h * 16384), smem8, tid);
    };
    auto STB = [&](int tt, int h) {
        stage_half8(BT, col0 + h * 128, K, KT(tt),
                    (unsigned)(((tt & 1) * 65536) + 32768 + h * 16384), smem8, tid);
    };

    // ---- prologue: tile0 fully, tile1 B-halves; leave 2 half-tiles in flight
    STB(0, 0); STB(0, 1); STA(0, 0); STA(0, 1); STB(1, 0); STB(1, 1);
    asm volatile("s_waitcnt vmcnt(4)");
    __builtin_amdgcn_s_barrier();

    for (int it = 0; it < nit; ++it) {
        const int t = it << 1;
        // -------- phases 1-4: tile t from buf0 --------
        read_A8<0>(av, arow + cs0, arow + cs1);
        read_B8<0>(bv[0], brow + cs0, brow + cs1);
        STA(t + 1, 0);
        PH_TAIL(0, 0, bv[0], 0)

        read_B8<1>(bv[1], brow + cs0, brow + cs1);
        STA(t + 1, 1);
        PH_TAIL(0, 1, bv[1], 0)

        read_A8<1>(av, arow + cs0, arow + cs1);
        STB(t + 2, 0);
        PH_TAIL(1, 0, bv[0], 0)

        STB(t + 2, 1);
        PH_TAIL(1, 1, bv[1], 1)

        // -------- phases 5-8: tile t+1 from buf1 --------
        read_A8<0>(av, arow + 65536u + cs0, arow + 65536u + cs1);
        read_B8<0>(bv[0], brow + 65536u + cs0, brow + 65536u + cs1);
        STA(t + 2, 0);
        PH_TAIL(0, 0, bv[0], 0)

        read_B8<1>(bv[1], brow + 65536u + cs0, brow + 65536u + cs1);
        STA(t + 2, 1);
        PH_TAIL(0, 1, bv[1], 0)

        read_A8<1>(av, arow + 65536u + cs0, arow + 65536u + cs1);
        STB(t + 3, 0);
        PH_TAIL(1, 0, bv[0], 0)

        STB(t + 3, 1);
        PH_TAIL(1, 1, bv[1], 1)
    }

    // ---- epilogue: fp32 partials
    float* po = part + (size_t)bz * M * N;
    const int gmb = row0 + wm * 128 + fq * 4;
    const int gnb = col0 + wn * 64 + fr;
    #pragma unroll
    for (int mi = 0; mi < 8; ++mi)
        #pragma unroll
        for (int nj = 0; nj < 4; ++nj)
            #pragma unroll
            for (int r2 = 0; r2 < 4; ++r2)
                po[(size_t)(gmb + mi * 16 + r2) * N + (gnb + nj * 16)] = acc[mi][nj][r2];
}

// ---------------------------------------------------------------------------
// fp32 [R][Cin] (optional rowscale) -> bf16 [R][Cpad], zero-padded
// ---------------------------------------------------------------------------
__global__ __launch_bounds__(256) void cast_rows_kernel(
    const float* __restrict__ src, const float* __restrict__ rowscale,
    ushort_t* __restrict__ dst, int R, int Cin, int Cpad)
{
    int idx = blockIdx.x * 256 + threadIdx.x;
    if (idx >= R * Cpad) return;
    int r = idx / Cpad, c = idx - r * Cpad;
    float v = 0.0f;
    if (c < Cin) {
        v = src[(size_t)r * Cin + c];
        if (rowscale) v *= rowscale[r];
    }
    dst[idx] = f2b(v);
}

// ---------------------------------------------------------------------------
// Fused gene pre-pass: per-row inverse L2 norm + scale + cast + pad.
// One block per row. Row is read twice (2nd pass L2-hot). K%4==0.
// ---------------------------------------------------------------------------
__global__ __launch_bounds__(256) void rownorm_cast_kernel(
    const float* __restrict__ x, ushort_t* __restrict__ dst, int K, int Kpad)
{
    const int row = blockIdx.x;
    const int tid = threadIdx.x;
    const float4* xp = (const float4*)(x + (size_t)row * K);
    const int K4  = K >> 2;
    const int Kp4 = Kpad >> 2;
    float s = 0.f;
    for (int k = tid; k < K4; k += 256) {
        float4 v = xp[k];
        s += v.x * v.x + v.y * v.y + v.z * v.z + v.w * v.w;
    }
    __shared__ float red[256];
    red[tid] = s;
    __syncthreads();
    for (int o = 128; o > 0; o >>= 1) {
        if (tid < o) red[tid] += red[tid + o];
        __syncthreads();
    }
    const float inv = 1.0f / fmaxf(sqrtf(red[0]), 1e-12f);
    ushort_t* dp = dst + (size_t)row * Kpad;
    for (int k = tid; k < Kp4; k += 256) {
        float4 v = (k < K4) ? xp[k] : make_float4(0.f, 0.f, 0.f, 0.f);
        ushort_t r0 = f2b(v.x * inv), r1 = f2b(v.y * inv);
        ushort_t r2 = f2b(v.z * inv), r3 = f2b(v.w * inv);
        *(uint2*)&dp[k * 4] = make_uint2((unsigned)r0 | ((unsigned)r1 << 16),
                                         (unsigned)r2 | ((unsigned)r3 << 16));
    }
}

// ---------------------------------------------------------------------------
// fp32 W[K][N] -> bf16 WT[N][Kpad] (transpose + pad), 32x32 LDS tiles.
// Rows n in [N, Npad) are written as zeros. Vectorized uint2 stores
// (requires Kpad%32==0, true for all uses).
// ---------------------------------------------------------------------------
__global__ __launch_bounds__(256) void castT_kernel(
    const float* __restrict__ W, ushort_t* __restrict__ WT,
    int K, int N, int Kpad, int Npad)
{
    __shared__ float t[32][33];
    const int nb = blockIdx.x * 32, kb = blockIdx.y * 32;
    const int x = threadIdx.x & 31, y = threadIdx.x >> 5;   // 32 x 8
    #pragma unroll
    for (int yy = 0; yy < 32; yy += 8) {
        int k = kb + y + yy, n = nb + x;
        t[y + yy][x] = (k < K && n < N) ? W[(size_t)k * N + n] : 0.0f;
    }
    __syncthreads();
    const int n8 = threadIdx.x >> 3;            // 0..31 (n within tile)
    const int kq = (threadIdx.x & 7) * 4;       // 0..28 (k quad)
    const int n  = nb + n8;
    const int kk = kb + kq;
    if (n < Npad && kk < Kpad) {
        ushort_t w0 = 0, w1 = 0, w2 = 0, w3 = 0;
        if (n < N) {
            w0 = f2b(t[kq + 0][n8]); w1 = f2b(t[kq + 1][n8]);
            w2 = f2b(t[kq + 2][n8]); w3 = f2b(t[kq + 3][n8]);
        }
        *(uint2*)&WT[(size_t)n * Kpad + kk] =
            make_uint2((unsigned)w0 | ((unsigned)w1 << 16),
                       (unsigned)w2 | ((unsigned)w3 << 16));
    }
}

// ---------------------------------------------------------------------------
// monotone float<->uint encoding for atomicMax on floats
// ---------------------------------------------------------------------------
__device__ __forceinline__ unsigned enc_f(float f) {
    unsigned u = __float_as_uint(f);
    return (u >> 31) ? ~u : (u | 0x80000000u);
}
__device__ __forceinline__ float dec_f(unsigned e) {
    return (e >> 31) ? __uint_as_float(e ^ 0x80000000u) : __uint_as_float(~e);
}

// ---------------------------------------------------------------------------
// Fully fused GAT stage, MFMA aggregation.
// One block (256 thr) per (graph, head). h bf16 [N][H*128].
// O[d][c] = sum_s At[s][d]*h[s][c] via mfma_16x16x32_bf16:
//   A = At^T as bf16 hi/lo pair (f32-equivalent alpha precision)
//   B = h^T in LDS with ROW STRIDE 80 B (20 banks: period-8 coverage of all
//       32 banks -> balanced transpose stores, 2-way (free) b128 reads)
// POOL=1: fused per-graph column max only.
// ---------------------------------------------------------------------------
#define ROWB 80   // bytes per 32-bf16 row (64 data + 16 pad)

__device__ __forceinline__ unsigned swz32(int row, int chunk) {
    return (unsigned)(row * ROWB + chunk * 16);
}

template <int POOL>
__global__ __launch_bounds__(256) void gat_fused_kernel(
    const ushort_t* __restrict__ h, const int* __restrict__ esrc,
    const int* __restrict__ edst, const float* __restrict__ a_src,
    const float* __restrict__ a_dst, const float* __restrict__ bias,
    ushort_t* __restrict__ out, int H)
{
    const int g    = blockIdx.x / H;
    const int hd   = blockIdx.x % H;
    const int tid  = threadIdx.x;
    const int lane = tid & 63;
    const int wave = tid >> 6;
    const int base = g * NPG;
    const int HC   = H * CCH;

    // uni: phase A = h_row bf16 [32][128] (8 KB); phase B = AtH+AtL (2x2560 B)
    __shared__ __align__(16) char uni[NPG * CCH * 2];          // 8 KB
    __shared__ __align__(16) ushort_t hT[CCH * (ROWB / 2)];    // 10 KB [c][s] stride-80
    __shared__ float At[NPG][NPG];                             // 4 KB, At[s][d]
    __shared__ float asv[CCH], adv[CCH];
    __shared__ float as_l[NPG], ad_l[NPG];
    __shared__ unsigned m_l[NPG];
    __shared__ float den_l[NPG];
    __shared__ float sc_l[EPG + NPG];
    __shared__ unsigned char s_l[EPG + NPG], d_l[EPG + NPG];

    ushort_t (*h_row)[CCH] = (ushort_t(*)[CCH])uni;
    ushort_t* AtH = (ushort_t*)uni;            // overlays h_row after its death
    ushort_t* AtL = (ushort_t*)(uni + 2560);

    // ---- hoist edge-index loads (hide HBM latency under staging) ----
    int es_r = 0, ed_r = 0;
    if (tid < EPG) {
        es_r = esrc[g * EPG + tid] - base;
        ed_r = edst[g * EPG + tid] - base;
    } else if (tid < EPG + NPG) {
        es_r = ed_r = tid - EPG;               // self-loop
    }

    // ---- stage h slice raw bf16 (16B/lane), zero At, load a-vectors ----
    const int srow = tid >> 3;                 // 0..31
    const int sch  = (tid & 7) * 16;           // elem offset, 16 elems/thread
    {
        const ushort_t* src = h + (size_t)(base + srow) * HC + hd * CCH + sch;
        uint4 v0 = *(const uint4*)(src);
        uint4 v1 = *(const uint4*)(src + 8);
        *(uint4*)&h_row[srow][sch]     = v0;
        *(uint4*)&h_row[srow][sch + 8] = v1;
    }
    #pragma unroll
    for (int i = tid; i < NPG * NPG; i += 256) ((float*)At)[i] = 0.0f;
    if (tid < CCH) asv[tid] = a_src[hd * CCH + tid];
    else           adv[tid - CCH] = a_dst[hd * CCH + tid - CCH];
    if (tid < NPG) { m_l[tid] = 0u; den_l[tid] = 0.0f; }
    __syncthreads();

    // ---- attention logits: 16 lanes per node, 2 passes, vector LDS reads --
    #pragma unroll
    for (int pass = 0; pass < 2; ++pass) {
        const int n  = pass * 16 + (tid >> 4);
        const int c0 = (tid & 15) * 8;
        uint4 hv = *(const uint4*)&h_row[n][c0];
        float4 sa0 = *(const float4*)&asv[c0];
        float4 sa1 = *(const float4*)&asv[c0 + 4];
        float4 da0 = *(const float4*)&adv[c0];
        float4 da1 = *(const float4*)&adv[c0 + 4];
        float h0 = __uint_as_float(hv.x << 16), h1 = __uint_as_float(hv.x & 0xffff0000u);
        float h2 = __uint_as_float(hv.y << 16), h3 = __uint_as_float(hv.y & 0xffff0000u);
        float h4 = __uint_as_float(hv.z << 16), h5 = __uint_as_float(hv.z & 0xffff0000u);
        float h6 = __uint_as_float(hv.w << 16), h7 = __uint_as_float(hv.w & 0xffff0000u);
        float s = h0 * sa0.x + h1 * sa0.y + h2 * sa0.z + h3 * sa0.w
                + h4 * sa1.x + h5 * sa1.y + h6 * sa1.z + h7 * sa1.w;
        float d = h0 * da0.x + h1 * da0.y + h2 * da0.z + h3 * da0.w
                + h4 * da1.x + h5 * da1.y + h6 * da1.z + h7 * da1.w;
        #pragma unroll
        for (int o = 8; o >= 1; o >>= 1) {
            s += __shfl_xor(s, o, 64);
            d += __shfl_xor(d, o, 64);
        }
        if ((tid & 15) == 0) { as_l[n] = s; ad_l[n] = d; }
    }
    // ---- transpose h_row -> hT (stride-80); thread owns col c, 16 s-rows --
    {
        const int c  = tid & 127;
        const int s0 = (tid >> 7) * 16;        // 0 or 16
        #pragma unroll
        for (int hh = 0; hh < 2; ++hh) {
            const int sb = s0 + hh * 8;
            unsigned pk[4];
            #pragma unroll
            for (int p = 0; p < 4; ++p) {
                unsigned lo = h_row[sb + 2 * p][c];
                unsigned hi = h_row[sb + 2 * p + 1][c];
                pk[p] = lo | (hi << 16);
            }
            *(uint4*)((char*)hT + swz32(c, sb >> 3)) = make_uint4(pk[0], pk[1], pk[2], pk[3]);
        }
    }
    __syncthreads();

    // ---- edge scores + segment max ----
    if (tid < EPG + NPG) {
        float e = as_l[es_r] + ad_l[ed_r];
        e = (e >= 0.0f) ? e : 0.2f * e;        // leaky_relu 0.2
        sc_l[tid] = e;
        s_l[tid] = (unsigned char)es_r;
        d_l[tid] = (unsigned char)ed_r;
        atomicMax(&m_l[ed_r], enc_f(e));
    }
    __syncthreads();

    // ---- exp + segment sum ----
    if (tid < EPG + NPG) {
        float ex = expf(sc_l[tid] - dec_f(m_l[d_l[tid]]));
        sc_l[tid] = ex;
        atomicAdd(&den_l[d_l[tid]], ex);
    }
    __syncthreads();

    // ---- scatter alpha into dense At[s][d] ----
    if (tid < EPG + NPG) {
        float al = sc_l[tid] / (den_l[d_l[tid]] + 1e-16f);
        atomicAdd(&At[s_l[tid]][d_l[tid]], al);
    }
    __syncthreads();

    // ---- At[s][d] -> At^T hi/lo bf16 rows (h_row dead; AtH/AtL overlay) ---
    {
        const int d  = tid >> 3;               // 0..31
        const int s4 = (tid & 7) * 4;          // 0,4,..,28
        float v0 = At[s4 + 0][d], v1 = At[s4 + 1][d];
        float v2 = At[s4 + 2][d], v3 = At[s4 + 3][d];
        ushort_t h0 = f2b(v0), h1 = f2b(v1), h2 = f2b(v2), h3 = f2b(v3);
        ushort_t l0 = f2b(v0 - b2f(h0)), l1 = f2b(v1 - b2f(h1));
        ushort_t l2 = f2b(v2 - b2f(h2)), l3 = f2b(v3 - b2f(h3));
        const unsigned a = swz32(d, s4 >> 3) + (unsigned)((s4 & 7) * 2);
        *(uint2*)((char*)AtH + a) = make_uint2((unsigned)h0 | ((unsigned)h1 << 16),
                                               (unsigned)h2 | ((unsigned)h3 << 16));
        *(uint2*)((char*)AtL + a) = make_uint2((unsigned)l0 | ((unsigned)l1 << 16),
                                               (unsigned)l2 | ((unsigned)l3 << 16));
    }
    __syncthreads();

    // ---- MFMA aggregation: per wave 1 d-block x 4 c-tiles, hi+lo ----
    const int fr = lane & 15, fq = lane >> 4;
    const int dblk  = wave & 1;
    const int cbase = (wave >> 1) * 64;

    bf16x8_t aH = *(const bf16x8_t*)((char*)AtH + swz32(dblk * 16 + fr, fq));
    bf16x8_t aL = *(const bf16x8_t*)((char*)AtL + swz32(dblk * 16 + fr, fq));
    bf16x8_t bfr[4];
    #pragma unroll
    for (int q = 0; q < 4; ++q)
        bfr[q] = *(const bf16x8_t*)((char*)hT + swz32(cbase + q * 16 + fr, fq));

    if (!POOL) __syncthreads();                // all hT reads done before reuse

    f32x4_t acc[4] = {};
    #pragma unroll
    for (int q = 0; q < 4; ++q) {
        acc[q] = __builtin_amdgcn_mfma_f32_16x16x32_bf16(aH, bfr[q], acc[q], 0, 0, 0);
        acc[q] = __builtin_amdgcn_mfma_f32_16x16x32_bf16(aL, bfr[q], acc[q], 0, 0, 0);
    }

    if (POOL) {
        float* pool2 = (float*)At;             // At dead; needs 256 floats
        #pragma unroll
        for (int q = 0; q < 4; ++q) {
            const int c = cbase + q * 16 + fr;
            const float bb = bias[hd * CCH + c];
            float m = -INFINITY;
            #pragma unroll
            for (int r = 0; r < 4; ++r) {
                float v = acc[q][r] + bb;
                v = (v > 0.0f) ? v : (expf(v) - 1.0f);
                m = fmaxf(m, v);
            }
            m = fmaxf(m, __shfl_xor(m, 16, 64));
            m = fmaxf(m, __shfl_xor(m, 32, 64));
            if (fq == 0) pool2[dblk * CCH + c] = m;
        }
        __syncthreads();
        if (tid < CCH)
            out[(size_t)g * CCH + tid] = f2b(fmaxf(pool2[tid], pool2[CCH + tid]));
    } else {
        // restage output tile in LDS (hT region, dead) for coalesced stores
        ushort_t (*o_l)[CCH] = (ushort_t(*)[CCH])hT;
        #pragma unroll
        for (int q = 0; q < 4; ++q) {
            const int c = cbase + q * 16 + fr;
            const float bb = bias[hd * CCH + c];
            #pragma unroll
            for (int r = 0; r < 4; ++r) {
                float v = acc[q][r] + bb;
                v = (v > 0.0f) ? v : (expf(v) - 1.0f);
                o_l[dblk * 16 + fq * 4 + r][c] = f2b(v);
            }
        }
        __syncthreads();
        ushort_t* dst = out + (size_t)(base + srow) * HC + hd * CCH + sch;
        *(uint4*)(dst)     = *(const uint4*)&o_l[srow][sch];
        *(uint4*)(dst + 8) = *(const uint4*)&o_l[srow][sch + 8];
    }
}

// ---------------------------------------------------------------------------
// Column-block copy helper (into concat buffers), strided src
// ---------------------------------------------------------------------------
__global__ __launch_bounds__(256) void copyb_kernel(
    ushort_t* __restrict__ dst, int dld, int doff,
    const ushort_t* __restrict__ src, int sld, int rows, int cols)
{
    int idx = blockIdx.x * 256 + threadIdx.x;
    if (idx >= rows * cols) return;
    int r = idx / cols, c = idx - r * cols;
    dst[(size_t)r * dld + doff + c] = src[(size_t)r * sld + c];
}

__global__ __launch_bounds__(256) void castcols_kernel(
    ushort_t* __restrict__ dst, int ld, int off,
    const float* __restrict__ src, int rows, int cols)
{
    int idx = blockIdx.x * 256 + threadIdx.x;
    if (idx >= rows * cols) return;
    int r = idx / cols, c = idx - r * cols;
    dst[(size_t)r * ld + off + c] = f2b(src[idx]);
}

// ---------------------------------------------------------------------------
// Final N_TASKS=1: out[b] = y[b,:256] . w + bout   (y bf16)
// ---------------------------------------------------------------------------
__global__ __launch_bounds__(256) void final_kernel(
    const ushort_t* __restrict__ y, const float* __restrict__ w,
    const float* __restrict__ b, float* __restrict__ out)
{
    const int row = blockIdx.x;
    const int tid = threadIdx.x;
    float v = b2f(y[(size_t)row * 256 + tid]) * w[tid];
    __shared__ float red[256];
    red[tid] = v;
    __syncthreads();
    for (int o = 128; o > 0; o >>= 1) {
        if (tid < o) red[tid] += red[tid + o];
        __syncthreads();
    }
    if (tid == 0) out[row] = red[0] + b[0];
}

// ---------------------------------------------------------------------------
// Host side
// ---------------------------------------------------------------------------
static inline void launch_gemm(const ushort_t* A, const ushort_t* BT,
                               const float* bias, ushort_t* C,
                               int M, int N, int K, int act, hipStream_t stream)
{
    dim3 grid(N / GBN, M / GBM);
    gemm_bf16_kernel<<<grid, 256, 0, stream>>>(A, BT, bias, C, M, N, K, act);
}

// split-K GEMM: partials into `part` (fp32), then reduce with bias+act
static inline void launch_gemm_sk(const ushort_t* A, const ushort_t* BT,
                                  const float* bias, ushort_t* C, float* part,
                                  int M, int N, int K, int S, int act,
                                  hipStream_t stream,
                                  int Nb = -1, int Cld = -1, int Coff = 0)
{
    if (Nb  < 0) Nb  = N;
    if (Cld < 0) Cld = N;
    const int iters = K / GBK;
    const int ipc   = (iters + S - 1) / S;         // iters per chunk
    const int S_eff = (iters + ipc - 1) / ipc;     // no empty chunks
    const int KC    = ipc * GBK;
    dim3 grid(N / GBN, M / GBM, S_eff);
    gemm_bf16_part_kernel<<<grid, 256, 0, stream>>>(A, BT, part, M, N, K, KC);
    const int MN = M * N;
    reduce_kernel<<<(MN / 4 + 255) / 256, 256, 0, stream>>>(
        part, bias, C, MN, N, S_eff, act, Nb, Cld, Coff);
}

// 8-phase 256^2 split-K GEMM path (M%256==0, N%256==0, K%128==0)
static inline void launch_gemm_8ph(const ushort_t* A, const ushort_t* BT,
                                   const float* bias, ushort_t* C, float* part,
                                   int M, int N, int K, int S, int act,
                                   hipStream_t stream,
                                   int Nb = -1, int Cld = -1, int Coff = 0)
{
    if (Nb  < 0) Nb  = N;
    if (Cld < 0) Cld = N;
    const int iters = K >> 7;                      // 128-K iterations
    const int ipc   = (iters + S - 1) / S;
    const int S_eff = (iters + ipc - 1) / ipc;
    const int gx = N >> 8, gy = M >> 8;
    const int nwg = gx * gy * S_eff;
    static bool attr_done = false;
    if (!attr_done) {
        (void)hipFuncSetAttribute((const void*)gemm_bf16_8ph_kernel,
                                  hipFuncAttributeMaxDynamicSharedMemorySize, 131072);
        attr_done = true;
    }
    gemm_bf16_8ph_kernel<<<dim3(nwg), 512, 131072, stream>>>(A, BT, part, M, N, K, ipc);
    const int MN = M * N;
    reduce_kernel<<<(MN / 4 + 255) / 256, 256, 0, stream>>>(
        part, bias, C, MN, N, S_eff, act, Nb, Cld, Coff);
}

static inline void launch_castT(const float* W, ushort_t* WT, int K, int N,
                                int Kpad, hipStream_t stream, int Npad = -1)
{
    if (Npad < 0) Npad = N;
    dim3 grid((Npad + 31) / 32, (Kpad + 31) / 32);
    castT_kernel<<<grid, 256, 0, stream>>>(W, WT, K, N, Kpad, Npad);
}

extern "C" void kernel_launch(void* const* d_in, const int* in_sizes, int n_in,
                              void* d_out, int out_size, void* d_ws, size_t ws_size,
                              hipStream_t stream)
{
    const float* x1      = (const float*)d_in[0];
    const float* x2      = (const float*)d_in[1];
    const float* gene    = (const float*)d_in[2];
    const float* drr     = (const float*)d_in[3];
    const float* drc     = (const float*)d_in[4];
    const float* prot    = (const float*)d_in[5];
    const int*   ei1     = (const int*)d_in[6];
    const int*   ei2     = (const int*)d_in[7];
    const float* W_gat1  = (const float*)d_in[9];
    const float* b_gat1  = (const float*)d_in[10];
    const float* a_src1  = (const float*)d_in[11];
    const float* a_dst1  = (const float*)d_in[12];
    const float* W_gat2  = (const float*)d_in[13];
    const float* b_gat2  = (const float*)d_in[14];
    const float* a_src2  = (const float*)d_in[15];
    const float* a_dst2  = (const float*)d_in[16];
    const float* W_fcg   = (const float*)d_in[17];
    const float* b_fcg   = (const float*)d_in[18];
    const float* Wr1     = (const float*)d_in[19];
    const float* br1     = (const float*)d_in[20];
    const float* Wr2     = (const float*)d_in[21];
    const float* br2     = (const float*)d_in[22];
    const float* Wr3     = (const float*)d_in[23];
    const float* br3     = (const float*)d_in[24];
    const float* Wp1     = (const float*)d_in[25];
    const float* bp1     = (const float*)d_in[26];
    const float* Wp2     = (const float*)d_in[27];
    const float* bp2     = (const float*)d_in[28];
    const float* Wp3     = (const float*)d_in[29];
    const float* bp3     = (const float*)d_in[30];
    const float* Wdrr    = (const float*)d_in[31];
    const float* bdrr    = (const float*)d_in[32];
    const float* Wdrc    = (const float*)d_in[33];
    const float* bdrc    = (const float*)d_in[34];
    const float* Wf1     = (const float*)d_in[35];
    const float* bf1     = (const float*)d_in[36];
    const float* Wf2     = (const float*)d_in[37];
    const float* bf2     = (const float*)d_in[38];
    const float* Wout    = (const float*)d_in[39];
    const float* bout    = (const float*)d_in[40];
    float* outp = (float*)d_out;

    char* ws = (char*)d_ws;
    size_t off = 0;
    auto alloc = [&](size_t bytes) -> char* {
        char* r = ws + off;
        off += (bytes + 255) & ~(size_t)255;
        return r;
    };

    char* BIG0 = alloc(134217728);
    char* BIG1 = alloc(67108864);

    ushort_t* go1f   = (ushort_t*)BIG0;
    ushort_t* h1     = (ushort_t*)BIG1;
    float*    part   = (float*)BIG1;
    ushort_t* WT_r1  = (ushort_t*)(BIG0 + 0);           // 2048x18048 = 73,924,608
    ushort_t* gene_nb= (ushort_t*)(BIG0 + 73924608);    // 1024x18048 = 36,962,304
    ushort_t* cell1  = (ushort_t*)(BIG0 + 110886912);   // 1024x2048  =  4,194,304
    ushort_t* WT_r2  = (ushort_t*)(BIG0 + 115081216);   // 512x2048   =  2,097,152
    ushort_t* WT_p2  = (ushort_t*)(BIG0 + 117178368);   // 512x1024   =  1,048,576
    ushort_t* WT_p1  = (ushort_t*)(BIG0 + 118226944);   // 1024x6784  = 13,895,680

    ushort_t* xb     = (ushort_t*)alloc((size_t)NNODES * 96 * 2);        // per-drug
    char*     h2reg  = alloc((size_t)2 * NNODES * 128 * 2);              // 16.8 MB
    char*     catreg = alloc((size_t)2 * 1024 * 2176 * 2);               //  8.9 MB
    ushort_t* h2f    = (ushort_t*)h2reg;     // drug phase
    ushort_t* protb  = (ushort_t*)h2reg;     // MLP phase alias (13.9 MB <= 16.8)
    ushort_t* cat1   = (ushort_t*)catreg;
    ushort_t* cat2   = (ushort_t*)(catreg + (size_t)1024 * 2176 * 2);
    ushort_t* pooled = (ushort_t*)alloc((size_t)2 * BATCH * 128 * 2);
    ushort_t* gpair  = (ushort_t*)alloc((size_t)2 * BATCH * 128 * 2);
    ushort_t* y1     = (ushort_t*)alloc((size_t)BATCH * 512 * 2);
    ushort_t* y2     = (ushort_t*)alloc((size_t)BATCH * 256 * 2);
    ushort_t* WT_g1  = (ushort_t*)alloc((size_t)1024 * 96 * 2);
    ushort_t* WT_g2  = (ushort_t*)alloc((size_t)128 * 1024 * 2);
    ushort_t* WT_fcg = (ushort_t*)alloc((size_t)128 * 128 * 2);
    ushort_t* WT_r3  = (ushort_t*)alloc((size_t)256 * 512 * 2);
    ushort_t* WT_p3  = (ushort_t*)alloc((size_t)256 * 512 * 2);
    ushort_t* WT_f2  = (ushort_t*)alloc((size_t)256 * 512 * 2);
    ushort_t* WT_drr = (ushort_t*)alloc((size_t)2304 * 2176 * 2);   // N padded
    ushort_t* WT_drc = (ushort_t*)alloc((size_t)2304 * 2176 * 2);   // N padded
    ushort_t* WT_f1  = (ushort_t*)alloc((size_t)512 * 4864 * 2);
    ushort_t* p1b    = (ushort_t*)alloc((size_t)1024 * 1024 * 2);
    ushort_t* p2b    = (ushort_t*)alloc((size_t)1024 * 512 * 2);
    ushort_t* cell2  = (ushort_t*)alloc((size_t)1024 * 512 * 2);
    ushort_t* ybuf   = (ushort_t*)alloc((size_t)1024 * 4864 * 2);

    const int E = in_sizes[6] / 2;   // 131072

    // ---------------- drug-phase weight casts ----------------
    launch_castT(W_gat1, WT_g1, INFEAT, 1024, 96, stream);
    launch_castT(W_gat2, WT_g2, 1024, 128, 1024, stream);
    launch_castT(W_fcg,  WT_fcg, 128, 128, 128, stream);

    // ---------------- drug branch: GAT1 per drug, write into shared go1f ---
    for (int drug = 0; drug < 2; drug++) {
        const float* x  = drug ? x2 : x1;
        const int*   es = (drug ? ei2 : ei1);
        const int*   ed = es + E;
        ushort_t* go1d = go1f + (size_t)drug * NNODES * 1024;

        cast_rows_kernel<<<(NNODES * 96 + 255) / 256, 256, 0, stream>>>(
            x, nullptr, xb, NNODES, INFEAT, 96);
        launch_gemm(xb, WT_g1, nullptr, h1, NNODES, 1024, 96, ACT_NONE, stream);
        gat_fused_kernel<0><<<BATCH * NHEAD, 256, 0, stream>>>(
            h1, es, ed, a_src1, a_dst1, b_gat1, go1d, NHEAD);
    }

    // ---------------- batched GAT2 GEMM (M=65536 -> 512 blocks) ------------
    launch_gemm(go1f, WT_g2, nullptr, h2f, 2 * NNODES, 128, 1024, ACT_NONE, stream);

    // BIG0 (go1f) now dead -> cast MLP-phase weights into it
    launch_castT(Wr1, WT_r1, GENE, 2048, GENEP, stream);
    launch_castT(Wr2, WT_r2, 2048, 512, 2048, stream);
    launch_castT(Wp1, WT_p1, PROT, 1024, PROTP, stream);
    launch_castT(Wp2, WT_p2, 1024, 512, 1024, stream);
    launch_castT(Wr3, WT_r3, 512, 256, 512, stream);
    launch_castT(Wp3, WT_p3, 512, 256, 512, stream);
    launch_castT(Wf2, WT_f2, 512, 256, 512, stream);
    launch_castT(Wdrr, WT_drr, 2176, 2176, 2176, stream, 2304);
    launch_castT(Wdrc, WT_drc, 2176, 2176, 2176, stream, 2304);
    launch_castT(Wf1, WT_f1, 4864, 512, 4864, stream);

    // ---------------- GAT2 fused (attn + softmax + agg + maxpool) ----------
    for (int drug = 0; drug < 2; drug++) {
        const int* es = (drug ? ei2 : ei1);
        const int* ed = es + E;
        gat_fused_kernel<1><<<BATCH, 256, 0, stream>>>(
            h2f + (size_t)drug * NNODES * 128, es, ed,
            a_src2, a_dst2, b_gat2, pooled + (size_t)drug * BATCH * 128, 1);
    }
    launch_gemm(pooled, WT_fcg, b_fcg, gpair, 2 * BATCH, 128, 128, ACT_RELU, stream);

    // ---------------- gene branch (fused norm+cast, 8-phase big-K GEMM) ----
    rownorm_cast_kernel<<<BATCH, 256, 0, stream>>>(gene, gene_nb, GENE, GENEP);
    launch_gemm_8ph(gene_nb, WT_r1, br1, cell1, part, BATCH, 2048, GENEP, 8, ACT_RELU, stream);
    launch_gemm_sk(cell1, WT_r2, br2, cell2, part, BATCH, 512, 2048, 8, ACT_RELU, stream);
    launch_gemm_sk(cell2, WT_r3, br3, ybuf, part, BATCH, 256, 512, 4, ACT_RELU, stream,
                   256, 4864, 4352);

    // ---------------- protein branch (8-phase for K=6784; protb aliases h2f)
    cast_rows_kernel<<<(BATCH * PROTP + 255) / 256, 256, 0, stream>>>(
        prot, nullptr, protb, BATCH, PROT, PROTP);
    launch_gemm_8ph(protb, WT_p1, bp1, p1b, part, BATCH, 1024, PROTP, 16, ACT_ELU, stream);
    launch_gemm_sk(p1b, WT_p2, bp2, p2b, part, BATCH, 512, 1024, 4, ACT_ELU, stream);
    launch_gemm_sk(p2b, WT_p3, bp3, ybuf, part, BATCH, 256, 512, 4, ACT_RELU, stream,
                   256, 4864, 4608);

    // ---------------- fingerprint fusion (8-phase, write into ybuf) --------
    {
        int n = BATCH * CCH;
        copyb_kernel<<<(n + 255) / 256, 256, 0, stream>>>(cat1, 2176, 0, gpair, 128, BATCH, CCH);
        copyb_kernel<<<(n + 255) / 256, 256, 0, stream>>>(cat2, 2176, 0, gpair + BATCH * CCH, 128, BATCH, CCH);
        n = BATCH * FPD;
        castcols_kernel<<<(n + 255) / 256, 256, 0, stream>>>(cat1, 2176, CCH, drr, BATCH, FPD);
        castcols_kernel<<<(n + 255) / 256, 256, 0, stream>>>(cat2, 2176, CCH, drc, BATCH, FPD);
    }
    launch_gemm_8ph(cat1, WT_drr, bdrr, ybuf, part, BATCH, 2304, 2176, 7, ACT_RELU, stream,
                    2176, 4864, 0);
    launch_gemm_8ph(cat2, WT_drc, bdrc, ybuf, part, BATCH, 2304, 2176, 7, ACT_RELU, stream,
                    2176, 4864, 2176);

    // ---------------- predictor ----------------
    launch_gemm_sk(ybuf, WT_f1, bf1, y1, part, BATCH, 512, 4864, 8, ACT_RELU, stream);
    launch_gemm_sk(y1, WT_f2, bf2, y2, part, BATCH, 256, 512, 4, ACT_RELU, stream);
    final_kernel<<<BATCH, 256, 0, stream>>>(y2, Wout, bout, outp);
}